// Round 6
// baseline (559.203 us; speedup 1.0000x reference)
//
#include <hip/hip_runtime.h>
#include <hip/hip_bf16.h>
#include <math.h>

// All inputs and the output are FLOAT32 (reference dtype). The "bf16" in the
// harness label is a literal string, not a dtype indicator.
//
// Upconv history:
//  R1/R3/R4: multi-output quad kernels (acc[4][*]) spill (allocator pins the
//    64-VGPR bucket; excess WRITE_SIZE is the tell).
//  R5: thread-per-output parity fold (k_upconv_p) removed the spill but made
//    weight loads PER-LANE (parity in threadIdx) -> 256 vector float4 loads/thread
//    through L1 -> slower than the uniform-weight original (108 vs 88us).
//  Now: parity from blockIdx.y; each thread does both x-parities -> weight
//    address wave-uniform (scalar s_load path), 2.25x fewer FMAs/output kept,
//    float2 coalesced stores, acc[2][16]+6 pixels ~55 live regs (fits 64 bucket).

#define HH 512
#define WWI 512
#define HWP (HH*WWI)

// ---------------- layer 0: 1x1 conv on upsampled 2x2 + leakyrelu + coordconv ----------------
__global__ void k_layer0(const float* __restrict__ xin, const float* __restrict__ w,
                         const float* __restrict__ bias, float* __restrict__ out)
{
  for (int idx = threadIdx.x; idx < 3*66*4; idx += blockDim.x) {
    int pos = idx & 3;
    int c = (idx >> 2) % 66;
    int b = idx / (66*4);
    float v;
    if (c < 64) {
      float a = bias[c];
      #pragma unroll
      for (int ci = 0; ci < 3; ci++) a += w[c*3+ci] * xin[b*3+ci];
      v = (a >= 0.f) ? a : 0.01f*a;
    } else {
      int xx = pos & 1, yy = pos >> 1;
      v = (c == 64) ? 2.f*(float)xx : 2.f*(float)yy;
    }
    out[idx] = v;
  }
}

__device__ __forceinline__ int refl_up(int t, int n) {
  t = (t < 0) ? -t : t;
  t = (t >= n) ? (2*(n-1) - t) : t;
  return t >> 1;
}

// ---------------- LDS conv: upsample x2 + reflect-pad + 3x3 + leakyrelu ----------------
template<int G>
__global__ void k_conv_lds(const float* __restrict__ in, float* __restrict__ out,
                           const float* __restrict__ w, const float* __restrict__ bias,
                           int B, int Cin, int CO, int COB, int Hin, int TR, int SPAN)
{
  extern __shared__ float lds[];
  const int Hout = Hin * 2;
  const int rowTiles = Hout / TR;
  const int coTiles = CO / COB;
  int bid = blockIdx.x;
  int tile = bid % rowTiles;
  int cot  = (bid / rowTiles) % coTiles;
  int b    = bid / (rowTiles * coTiles);
  int tr0  = tile * TR;
  int co_base = cot * COB;

  int r0 = tr0/2 - 1;
  if (r0 < 0) r0 = 0;
  if (r0 > Hin - SPAN) r0 = Hin - SPAN;

  float* wlds = lds;                    // COB*Cin*9
  float* blds = wlds + COB*Cin*9;       // COB
  float* ilds = blds + COB;             // Cin*SPAN*Hin

  int nt = blockDim.x, tid = threadIdx.x;

  const float* wsrc = w + (size_t)co_base*Cin*9;
  for (int i = tid; i < COB*Cin*9; i += nt) wlds[i] = wsrc[i];
  for (int i = tid; i < COB; i += nt) blds[i] = bias[co_base + i];
  int icount = Cin*SPAN*Hin;
  for (int i = tid; i < icount; i += nt) {
    int col = i % Hin;
    int r = (i / Hin) % SPAN;
    int ci = i / (Hin*SPAN);
    ilds[i] = in[(((size_t)b*Cin + ci)*Hin + (r0 + r))*Hin + col];
  }
  __syncthreads();

  int npix = TR * Hout;
  int ngr = COB / G;
  int items = ngr * npix;
  for (int it = tid; it < items; it += nt) {
    int pix = it % npix;
    int cg = it / npix;
    int x = pix % Hout;
    int y = tr0 + pix / Hout;

    int ry[3], rx[3];
    #pragma unroll
    for (int d = 0; d < 3; d++) {
      int s = refl_up(y - 1 + d, Hout) - r0;
      s = (s < 0) ? 0 : s;
      s = (s > SPAN-1) ? SPAN-1 : s;
      ry[d] = s;
      rx[d] = refl_up(x - 1 + d, Hout);
    }

    float acc[G];
    #pragma unroll
    for (int j = 0; j < G; j++) acc[j] = blds[cg*G + j];

    for (int ci = 0; ci < Cin; ci++) {
      const float* ib = ilds + (size_t)ci*SPAN*Hin;
      float p[9];
      #pragma unroll
      for (int dy = 0; dy < 3; dy++)
        #pragma unroll
        for (int dx = 0; dx < 3; dx++)
          p[dy*3+dx] = ib[ry[dy]*Hin + rx[dx]];
      const float* wc = wlds + ((size_t)(cg*G)*Cin + ci)*9;
      #pragma unroll
      for (int j = 0; j < G; j++) {
        #pragma unroll
        for (int k = 0; k < 9; k++) acc[j] += wc[(size_t)j*Cin*9 + k] * p[k];
      }
    }

    #pragma unroll
    for (int j = 0; j < G; j++) {
      float v = acc[j];
      v = (v >= 0.f) ? v : 0.01f*v;
      out[(((size_t)b*CO + co_base + cg*G + j)*Hout + y)*Hout + x] = v;
    }
  }
}

// ---------------- weight folding for upsample-conv parity decomposition ----------------
// upsample x2 + reflect-pad + 3x3 VALID conv == per-output-parity 2x2 conv on the
// ORIGINAL (pre-upsample) image:
//   even y (py=0): rows (Y-1, Y), weights (w0, w1+w2); odd y: rows (Y, Y+1), (w0+w1, w2).
//   Same in x. Border reflection == clamping the outer source row/col.
// Folded layout: f[((co*Cin + ci)*16) + p*4 + ky*2 + kx], p = py*2+px. 16B-aligned float4 per p.
__global__ void k_foldw3(const float* __restrict__ w6, const float* __restrict__ w7,
                         const float* __restrict__ w8, float* __restrict__ f6,
                         float* __restrict__ f7, float* __restrict__ f8)
{
  int idx = blockIdx.x*blockDim.x + threadIdx.x;
  const float* w; float* f; int n;
  if (idx < 512)       { w = w6; f = f6; n = idx; }        // CO=16, Cin=32
  else if (idx < 768)  { w = w7; f = f7; n = idx - 512; }  // CO=16, Cin=16
  else if (idx < 1024) { w = w8; f = f8; n = idx - 768; }  // CO=16, Cin=16
  else return;

  const float* ws = w + (size_t)n*9;
  float W[9];
  #pragma unroll
  for (int k = 0; k < 9; k++) W[k] = ws[k];

  // row folds a[py][ky][c]
  float a[2][2][3];
  #pragma unroll
  for (int c = 0; c < 3; c++) {
    a[0][0][c] = W[c];          a[0][1][c] = W[3+c] + W[6+c];
    a[1][0][c] = W[c] + W[3+c]; a[1][1][c] = W[6+c];
  }
  float* fo = f + (size_t)n*16;
  #pragma unroll
  for (int py = 0; py < 2; py++)
    #pragma unroll
    for (int px = 0; px < 2; px++) {
      int p = py*2 + px;
      #pragma unroll
      for (int ky = 0; ky < 2; ky++) {
        float kx0 = (px == 0) ? a[py][ky][0] : (a[py][ky][0] + a[py][ky][1]);
        float kx1 = (px == 0) ? (a[py][ky][1] + a[py][ky][2]) : a[py][ky][2];
        fo[p*4 + ky*2 + 0] = kx0;
        fo[p*4 + ky*2 + 1] = kx1;
      }
    }
}

// ---------------- parity-pair upconv: blockIdx.y = py (wave-uniform weights) ----------------
// One thread = one input column position (b,Y,X) at row-parity py -> outputs
// (2Y+py, 2X) and (2Y+py, 2X+1). Weight address depends only on py (SGPR) and
// loop counters -> scalar s_load path (zero vector-memory weight traffic).
// Per output: 3 pixel loads/ci-pair-shared, 1024 FMAs (vs 2304), float2 store.
template<int CO>
__global__ void k_upconv_p2(const float* __restrict__ in, float* __restrict__ out,
                            const float* __restrict__ wfold, const float* __restrict__ bias,
                            int B, int Cin, int Hin)
{
  int items = B * Hin * Hin;
  int idx = blockIdx.x*blockDim.x + threadIdx.x;
  if (idx >= items) return;
  int py = blockIdx.y;              // 0 or 1, SGPR-uniform
  int Hout = Hin * 2;
  int X = idx % Hin;
  int Y = (idx / Hin) % Hin;
  int b = idx / (Hin * Hin);

  // folded source rows (reflection == clamp at borders)
  int r_lo = py ? Y : (Y > 0 ? Y-1 : 0);
  int r_hi = py ? (Y < Hin-1 ? Y+1 : Hin-1) : Y;
  int xm1 = (X > 0) ? X-1 : 0;
  int xp1 = (X < Hin-1) ? X+1 : Hin-1;

  float acc0[CO], acc1[CO];
  #pragma unroll
  for (int co = 0; co < CO; co++) { float bv = bias[co]; acc0[co] = bv; acc1[co] = bv; }

  const size_t plane = (size_t)Hin * Hin;
  const float* ibase = in + (size_t)b * Cin * plane;
  const float* wb = wfold + (size_t)py * 8;   // parities 2py (offset 0) and 2py+1 (offset 4)

  for (int ci = 0; ci < Cin; ci++) {
    const float* ip = ibase + (size_t)ci * plane;
    const float* rl = ip + (size_t)r_lo * Hin;
    const float* rh = ip + (size_t)r_hi * Hin;
    float a0 = rl[xm1], a1 = rl[X], a2 = rl[xp1];
    float b0 = rh[xm1], b1 = rh[X], b2 = rh[xp1];

    const float* wc = wb + (size_t)ci * 16;
    #pragma unroll
    for (int co = 0; co < CO; co++) {
      const float* wp = wc + (size_t)co * Cin * 16;     // uniform address
      float4 w0 = *reinterpret_cast<const float4*>(wp);       // px=0: cols (X-1, X)
      float4 w1 = *reinterpret_cast<const float4*>(wp + 4);   // px=1: cols (X, X+1)
      acc0[co] += w0.x*a0 + w0.y*a1 + w0.z*b0 + w0.w*b1;
      acc1[co] += w1.x*a1 + w1.y*a2 + w1.z*b1 + w1.w*b2;
    }
  }

  int y = 2*Y + py;
  size_t oplane = (size_t)Hout * Hout;
  float* obase = out + (size_t)b * CO * oplane + (size_t)y * Hout + 2*X;
  #pragma unroll
  for (int co = 0; co < CO; co++) {
    float v0 = acc0[co]; v0 = (v0 >= 0.f) ? v0 : 0.01f*v0;
    float v1 = acc1[co]; v1 = (v1 >= 0.f) ? v1 : 0.01f*v1;
    *reinterpret_cast<float2*>(obase + (size_t)co * oplane) = make_float2(v0, v1);
  }
}

// ---------------- final: reflect-pad + 3x3 conv (16 -> 6) + tanh ----------------
__global__ void k_final(const float* __restrict__ in, float* __restrict__ out,
                        const float* __restrict__ w, const float* __restrict__ bias)
{
  int idx = blockIdx.x*blockDim.x + threadIdx.x;
  int total = 3 * HWP;
  if (idx >= total) return;
  int x = idx & (WWI-1);
  int y = (idx >> 9) & (HH-1);
  int b = idx / HWP;

  int ry[3], rx[3];
  #pragma unroll
  for (int d = 0; d < 3; d++) {
    int t = y - 1 + d;
    t = (t < 0) ? -t : t;
    ry[d] = (t >= HH) ? (2*(HH-1) - t) : t;
    t = x - 1 + d;
    t = (t < 0) ? -t : t;
    rx[d] = (t >= WWI) ? (2*(WWI-1) - t) : t;
  }

  float acc[6];
  #pragma unroll
  for (int co = 0; co < 6; co++) acc[co] = bias[co];

  for (int ci = 0; ci < 16; ci++) {
    const float* ib = in + ((size_t)(b*16) + ci) * HWP;
    float p[9];
    #pragma unroll
    for (int dy = 0; dy < 3; dy++)
      #pragma unroll
      for (int dx = 0; dx < 3; dx++)
        p[dy*3+dx] = ib[ry[dy]*WWI + rx[dx]];
    const float* wc = w + ci*9;
    #pragma unroll
    for (int co = 0; co < 6; co++) {
      const float* wcc = wc + co*16*9;
      #pragma unroll
      for (int k = 0; k < 9; k++) acc[co] += wcc[k] * p[k];
    }
  }

  int pix = y*WWI + x;
  #pragma unroll
  for (int co = 0; co < 6; co++)
    out[((size_t)(b*6) + co)*HWP + pix] = tanhf(acc[co]);
}

// ---------------- blending: fused grid-sample + weighting (all fp32) ----------------
__global__ void k_blend(const float* __restrict__ xin, const float* __restrict__ neighbors,
                        const int* __restrict__ aidx, const float* __restrict__ albedos,
                        const float* __restrict__ flows, float* __restrict__ out)
{
  int idx = blockIdx.x*blockDim.x + threadIdx.x;
  if (idx >= HWP) return;
  int xo = idx & (WWI-1);
  int yo = idx >> 9;

  float xv[9];
  #pragma unroll
  for (int i = 0; i < 9; i++) xv[i] = xin[i];

  float f0[6];
  #pragma unroll
  for (int c = 0; c < 6; c++) f0[c] = flows[(size_t)c*HWP + idx];

  const float* alb = albedos + (size_t)aidx[0]*3*HWP;
  float albp[3];
  #pragma unroll
  for (int ch = 0; ch < 3; ch++) albp[ch] = alb[(size_t)ch*HWP + idx];

  float num0 = 0.f, num1 = 0.f, num2 = 0.f;
  float wsum = 0.f;

  #pragma unroll
  for (int n = 0; n < 2; n++) {
    float dl = xv[0] - xv[(n+1)*3 + 0];
    float dv = xv[1] - xv[(n+1)*3 + 1];
    float dt = xv[2] - xv[(n+1)*3 + 2];
    bool fl = fabsf(dl) > 0.f;

    float ofx = dl*f0[0] + dv*f0[2] + dt*f0[4];
    float ofy = dl*f0[1] + dv*f0[3] + dt*f0[5];

    float gx = ((-1.f + (2.f/511.f)*(float)xo) + ofx + 1.f)*256.f - 0.5f;
    float gy = ((-1.f + (2.f/511.f)*(float)yo) + ofy + 1.f)*256.f - 0.5f;
    gx = fminf(fmaxf(gx, 0.f), 511.f);
    gy = fminf(fmaxf(gy, 0.f), 511.f);

    float x0f = floorf(gx), y0f = floorf(gy);
    float wx = gx - x0f, wy = gy - y0f;
    int x0i = (int)x0f, y0i = (int)y0f;
    int x1i = min(x0i + 1, WWI-1), y1i = min(y0i + 1, HH-1);

    float cw[4] = {(1.f-wx)*(1.f-wy), wx*(1.f-wy), (1.f-wx)*wy, wx*wy};
    int   cp[4] = {y0i*WWI + x0i, y0i*WWI + x1i, y1i*WWI + x0i, y1i*WWI + x1i};

    const float* nb = neighbors + (size_t)n*3*HWP;
    const float* Fn = flows + (size_t)(n+1)*6*HWP;

    float s0=0.f,s1=0.f,s2=0.f;
    float l0=0.f,l1=0.f,v0=0.f,v1=0.f,t0=0.f,t1=0.f;
    #pragma unroll
    for (int c = 0; c < 4; c++) {
      int p = cp[c];
      float ww = cw[c];
      float n0 = nb[p];
      float n1 = nb[HWP + p];
      float n2 = nb[2*HWP + p];
      if (fl) {
        n0 /= alb[p];
        n1 /= alb[HWP + p];
        n2 /= alb[2*HWP + p];
      }
      s0 += ww*n0; s1 += ww*n1; s2 += ww*n2;
      l0 += ww*Fn[p];             l1 += ww*Fn[HWP + p];
      v0 += ww*Fn[2*HWP + p];     v1 += ww*Fn[3*HWP + p];
      t0 += ww*Fn[4*HWP + p];     t1 += ww*Fn[5*HWP + p];
    }

    float wi0 = fl ? s0*albp[0] : s0;
    float wi1 = fl ? s1*albp[1] : s1;
    float wi2 = fl ? s2*albp[2] : s2;

    float obx = dl*l0 + dv*v0 + dt*t0;
    float oby = dl*l1 + dv*v1 + dt*t1;
    float dist = fabsf(ofx - obx) + fabsf(ofy - oby);
    float wgt = expf(-51.2f * dist);

    wsum += wgt;
    num0 += wgt*wi0; num1 += wgt*wi1; num2 += wgt*wi2;
  }

  float inv = 1.f / (wsum + 1e-5f);
  out[idx]         = num0*inv;
  out[HWP + idx]   = num1*inv;
  out[2*HWP + idx] = num2*inv;
}

// ---------------- launch ----------------
extern "C" void kernel_launch(void* const* d_in, const int* in_sizes, int n_in,
                              void* d_out, int out_size, void* d_ws, size_t ws_size,
                              hipStream_t stream) {
  const float* x         = (const float*)d_in[0];
  const float* neighbors = (const float*)d_in[1];
  const int*   aidx      = (const int*)d_in[2];
  const float* wts[10];
  const float* bis[10];
  for (int i = 0; i < 9; i++) { wts[i] = (const float*)d_in[3+2*i]; bis[i] = (const float*)d_in[4+2*i]; }
  wts[9] = (const float*)d_in[21];   // wf
  bis[9] = (const float*)d_in[22];   // bf
  const float* albedos = (const float*)d_in[23];

  float* wk   = (float*)d_ws;
  float* bufS = wk;                   // 792 floats (layer0 out)
  float* bufA = wk + 800;             // up to 4,718,592 floats
  float* bufB = bufA + 4718592;       // up to 12,582,912 floats
  size_t need = (size_t)(800 + 4718592 + 12582912) * 4;
  if (ws_size < need) return;

  // Folded-weight buffers live in bufA slack [3,200,000, 3,216,384):
  // above L7's peak use (3,145,728 floats) and only overwritten by k_final
  // (4,718,592 floats) AFTER L8 has consumed them. No workspace growth.
  float* wf6 = bufA + 3200000;            // 16*32*16 = 8192 floats
  float* wf7 = wf6 + 8192;                // 16*16*16 = 4096 floats
  float* wf8 = wf7 + 4096;                // 16*16*16 = 4096 floats
  k_foldw3<<<4, 256, 0, stream>>>(wts[6], wts[7], wts[8], wf6, wf7, wf8);

  k_layer0<<<1, 256, 0, stream>>>(x, wts[0], bis[0], bufS);

  auto spanOf = [](int Hin, int TR) { int s = TR/2 + 2; return (s > Hin) ? Hin : s; };
  auto ldsB = [&](int COB, int Cin, int Hin, int TR) {
    return (size_t)(COB*Cin*9 + COB + Cin*spanOf(Hin,TR)*Hin) * 4;
  };

  // L1: Cin=66 CO=64 Hin=2  | COB=16 TR=4 G=1 | blocks 3*4*1=12
  k_conv_lds<1><<<12, 256, ldsB(16,66,2,4), stream>>>(bufS, bufA, wts[1], bis[1],
                                                      3, 66, 64, 16, 2, 4, spanOf(2,4));
  // L2: Cin=64 CO=64 Hin=4  | COB=8 TR=8 G=1 | blocks 3*8*1=24
  k_conv_lds<1><<<24, 256, ldsB(8,64,4,8), stream>>>(bufA, bufB, wts[2], bis[2],
                                                     3, 64, 64, 8, 4, 8, spanOf(4,8));
  // L3: Cin=64 CO=32 Hin=8  | COB=4 TR=16 G=2 | blocks 3*8*1=24
  k_conv_lds<2><<<24, 256, ldsB(4,64,8,16), stream>>>(bufB, bufA, wts[3], bis[3],
                                                      3, 64, 32, 4, 8, 16, spanOf(8,16));
  // L4: Cin=32 CO=32 Hin=16 | COB=8 TR=8 G=2 | blocks 3*4*4=48
  k_conv_lds<2><<<48, 256, ldsB(8,32,16,8), stream>>>(bufA, bufB, wts[4], bis[4],
                                                      3, 32, 32, 8, 16, 8, spanOf(16,8));
  // L5: Cin=32 CO=32 Hin=32 | COB=8 TR=8 G=4 | blocks 3*4*8=96
  k_conv_lds<4><<<96, 256, ldsB(8,32,32,8), stream>>>(bufB, bufA, wts[5], bis[5],
                                                      3, 32, 32, 8, 32, 8, spanOf(32,8));

  auto blocks = [](int total){ return (total + 255) / 256; };
  // L6-L8: parity-pair upconv, gridDim.y = row parity (wave-uniform weights)
  {
    dim3 g6(blocks(3*64*64), 2), g7(blocks(3*128*128), 2), g8(blocks(3*256*256), 2);
    k_upconv_p2<16><<<g6, 256, 0, stream>>>(bufA, bufB, wf6, bis[6], 3, 32, 64);
    k_upconv_p2<16><<<g7, 256, 0, stream>>>(bufB, bufA, wf7, bis[7], 3, 16, 128);
    k_upconv_p2<16><<<g8, 256, 0, stream>>>(bufA, bufB, wf8, bis[8], 3, 16, 256);
  }

  k_final<<<blocks(3*HWP), 256, 0, stream>>>(bufB, bufA, wts[9], bis[9]);
  k_blend<<<blocks(HWP), 256, 0, stream>>>(x, neighbors, aidx, albedos, bufA, (float*)d_out);
}

// Round 7
// 460.149 us; speedup vs baseline: 1.2153x; 1.2153x over previous
//
#include <hip/hip_runtime.h>
#include <hip/hip_bf16.h>
#include <math.h>

// All inputs and the output are FLOAT32 (reference dtype). The "bf16" in the
// harness label is a literal string, not a dtype indicator.
//
// Upconv history:
//  R1/R3/R4: multi-output quad kernels (acc[4][*]) spill (allocator pins the
//    64-VGPR bucket; excess WRITE_SIZE is the tell).
//  R5: thread-per-output parity fold: no spill, but per-lane weight addresses
//    -> 256 vector float4 loads/thread through L1 -> 108us (slower than base).
//  R6: blockIdx.y parity (wave-uniform weights -> s_load path): L7/L8 improved
//    but L6 = 86us: 96-block grid (1 wave/SIMD) x 512 serial s_load->FMA
//    dependent chains = latency-bound (VALUBusy 3.2%, Occ 4%).
//  Now: weights staged in LDS (all 4 parity sets), thread-per-output for max
//    grid. Per-lane parity is FREE in LDS: py wave-uniform, px alternates ->
//    2 distinct ds_read addresses/wave = broadcast (2-way conflict free, m136).

#define HH 512
#define WWI 512
#define HWP (HH*WWI)

// ---------------- layer 0: 1x1 conv on upsampled 2x2 + leakyrelu + coordconv ----------------
__global__ void k_layer0(const float* __restrict__ xin, const float* __restrict__ w,
                         const float* __restrict__ bias, float* __restrict__ out)
{
  for (int idx = threadIdx.x; idx < 3*66*4; idx += blockDim.x) {
    int pos = idx & 3;
    int c = (idx >> 2) % 66;
    int b = idx / (66*4);
    float v;
    if (c < 64) {
      float a = bias[c];
      #pragma unroll
      for (int ci = 0; ci < 3; ci++) a += w[c*3+ci] * xin[b*3+ci];
      v = (a >= 0.f) ? a : 0.01f*a;
    } else {
      int xx = pos & 1, yy = pos >> 1;
      v = (c == 64) ? 2.f*(float)xx : 2.f*(float)yy;
    }
    out[idx] = v;
  }
}

__device__ __forceinline__ int refl_up(int t, int n) {
  t = (t < 0) ? -t : t;
  t = (t >= n) ? (2*(n-1) - t) : t;
  return t >> 1;
}

// ---------------- LDS conv: upsample x2 + reflect-pad + 3x3 + leakyrelu ----------------
template<int G>
__global__ void k_conv_lds(const float* __restrict__ in, float* __restrict__ out,
                           const float* __restrict__ w, const float* __restrict__ bias,
                           int B, int Cin, int CO, int COB, int Hin, int TR, int SPAN)
{
  extern __shared__ float lds[];
  const int Hout = Hin * 2;
  const int rowTiles = Hout / TR;
  const int coTiles = CO / COB;
  int bid = blockIdx.x;
  int tile = bid % rowTiles;
  int cot  = (bid / rowTiles) % coTiles;
  int b    = bid / (rowTiles * coTiles);
  int tr0  = tile * TR;
  int co_base = cot * COB;

  int r0 = tr0/2 - 1;
  if (r0 < 0) r0 = 0;
  if (r0 > Hin - SPAN) r0 = Hin - SPAN;

  float* wlds = lds;                    // COB*Cin*9
  float* blds = wlds + COB*Cin*9;       // COB
  float* ilds = blds + COB;             // Cin*SPAN*Hin

  int nt = blockDim.x, tid = threadIdx.x;

  const float* wsrc = w + (size_t)co_base*Cin*9;
  for (int i = tid; i < COB*Cin*9; i += nt) wlds[i] = wsrc[i];
  for (int i = tid; i < COB; i += nt) blds[i] = bias[co_base + i];
  int icount = Cin*SPAN*Hin;
  for (int i = tid; i < icount; i += nt) {
    int col = i % Hin;
    int r = (i / Hin) % SPAN;
    int ci = i / (Hin*SPAN);
    ilds[i] = in[(((size_t)b*Cin + ci)*Hin + (r0 + r))*Hin + col];
  }
  __syncthreads();

  int npix = TR * Hout;
  int ngr = COB / G;
  int items = ngr * npix;
  for (int it = tid; it < items; it += nt) {
    int pix = it % npix;
    int cg = it / npix;
    int x = pix % Hout;
    int y = tr0 + pix / Hout;

    int ry[3], rx[3];
    #pragma unroll
    for (int d = 0; d < 3; d++) {
      int s = refl_up(y - 1 + d, Hout) - r0;
      s = (s < 0) ? 0 : s;
      s = (s > SPAN-1) ? SPAN-1 : s;
      ry[d] = s;
      rx[d] = refl_up(x - 1 + d, Hout);
    }

    float acc[G];
    #pragma unroll
    for (int j = 0; j < G; j++) acc[j] = blds[cg*G + j];

    for (int ci = 0; ci < Cin; ci++) {
      const float* ib = ilds + (size_t)ci*SPAN*Hin;
      float p[9];
      #pragma unroll
      for (int dy = 0; dy < 3; dy++)
        #pragma unroll
        for (int dx = 0; dx < 3; dx++)
          p[dy*3+dx] = ib[ry[dy]*Hin + rx[dx]];
      const float* wc = wlds + ((size_t)(cg*G)*Cin + ci)*9;
      #pragma unroll
      for (int j = 0; j < G; j++) {
        #pragma unroll
        for (int k = 0; k < 9; k++) acc[j] += wc[(size_t)j*Cin*9 + k] * p[k];
      }
    }

    #pragma unroll
    for (int j = 0; j < G; j++) {
      float v = acc[j];
      v = (v >= 0.f) ? v : 0.01f*v;
      out[(((size_t)b*CO + co_base + cg*G + j)*Hout + y)*Hout + x] = v;
    }
  }
}

// ---------------- weight folding for upsample-conv parity decomposition ----------------
// upsample x2 + reflect-pad + 3x3 VALID conv == per-output-parity 2x2 conv on the
// ORIGINAL (pre-upsample) image:
//   even y (py=0): rows (Y-1, Y), weights (w0, w1+w2); odd y: rows (Y, Y+1), (w0+w1, w2).
//   Same in x. Border reflection == clamping the outer source row/col.
// Folded layout: f[((co*Cin + ci)*16) + p*4 + ky*2 + kx], p = py*2+px. 16B-aligned float4 per p.
__global__ void k_foldw3(const float* __restrict__ w6, const float* __restrict__ w7,
                         const float* __restrict__ w8, float* __restrict__ f6,
                         float* __restrict__ f7, float* __restrict__ f8)
{
  int idx = blockIdx.x*blockDim.x + threadIdx.x;
  const float* w; float* f; int n;
  if (idx < 512)       { w = w6; f = f6; n = idx; }        // CO=16, Cin=32
  else if (idx < 768)  { w = w7; f = f7; n = idx - 512; }  // CO=16, Cin=16
  else if (idx < 1024) { w = w8; f = f8; n = idx - 768; }  // CO=16, Cin=16
  else return;

  const float* ws = w + (size_t)n*9;
  float W[9];
  #pragma unroll
  for (int k = 0; k < 9; k++) W[k] = ws[k];

  // row folds a[py][ky][c]
  float a[2][2][3];
  #pragma unroll
  for (int c = 0; c < 3; c++) {
    a[0][0][c] = W[c];          a[0][1][c] = W[3+c] + W[6+c];
    a[1][0][c] = W[c] + W[3+c]; a[1][1][c] = W[6+c];
  }
  float* fo = f + (size_t)n*16;
  #pragma unroll
  for (int py = 0; py < 2; py++)
    #pragma unroll
    for (int px = 0; px < 2; px++) {
      int p = py*2 + px;
      #pragma unroll
      for (int ky = 0; ky < 2; ky++) {
        float kx0 = (px == 0) ? a[py][ky][0] : (a[py][ky][0] + a[py][ky][1]);
        float kx1 = (px == 0) ? (a[py][ky][1] + a[py][ky][2]) : a[py][ky][2];
        fo[p*4 + ky*2 + 0] = kx0;
        fo[p*4 + ky*2 + 1] = kx1;
      }
    }
}

// ---------------- LDS-weight parity upconv: one thread per OUTPUT pixel ----------------
// All 4 parity weight sets staged in LDS ([p][ci][co] float4). Per-lane parity read
// is a 2-address broadcast (py wave-uniform, px alternates) -> conflict-free.
// Per output: 4 pixel loads, Cin*CO ds_read_b128 (broadcast), Cin*CO*4 FMAs.
// acc[CO]=16 regs + 4 pixels: proven no-spill footprint. Grid = one thread/output.
template<int CO>
__global__ void k_upconv_w(const float* __restrict__ in, float* __restrict__ out,
                           const float* __restrict__ wfold, const float* __restrict__ bias,
                           int B, int Cin, int Hin)
{
  extern __shared__ float4 wlds4[];           // [4][Cin][CO] float4
  int nt = blockDim.x, tid = threadIdx.x;
  int nw = Cin * CO * 4;                      // total float4s
  // src float4 index s = (co*Cin+ci)*4 + p  (global layout ((co*Cin+ci)*16 + p*4 + k))
  // dst float4 index   = (p*Cin + ci)*CO + co
  const float4* wsrc = reinterpret_cast<const float4*>(wfold);
  for (int s = tid; s < nw; s += nt) {
    int p = s & 3;
    int r = s >> 2;            // co*Cin + ci
    int ci = r % Cin;
    int co = r / Cin;
    wlds4[(p*Cin + ci)*CO + co] = wsrc[s];
  }
  __syncthreads();

  int Hout = Hin * 2;
  int total = B * Hout * Hout;
  int idx = blockIdx.x*nt + tid;
  if (idx >= total) return;
  int x = idx % Hout;
  int y = (idx / Hout) % Hout;
  int b = idx / (Hout * Hout);

  int X = x >> 1, Y = y >> 1;
  int px = x & 1, py = y & 1;

  // folded source rows/cols (reflection == clamp at borders)
  int r_lo = py ? Y : (Y > 0 ? Y-1 : 0);
  int r_hi = py ? (Y < Hin-1 ? Y+1 : Hin-1) : Y;
  int c_lo = px ? X : (X > 0 ? X-1 : 0);
  int c_hi = px ? (X < Hin-1 ? X+1 : Hin-1) : X;

  float acc[CO];
  #pragma unroll
  for (int co = 0; co < CO; co++) acc[co] = bias[co];

  const size_t plane = (size_t)Hin * Hin;
  const float* ibase = in + (size_t)b * Cin * plane;
  const float4* wb = wlds4 + (py*2 + px) * Cin * CO;

  for (int ci = 0; ci < Cin; ci++) {
    const float* ip = ibase + (size_t)ci * plane;
    const float* rl = ip + (size_t)r_lo * Hin;
    const float* rh = ip + (size_t)r_hi * Hin;
    float p00 = rl[c_lo], p01 = rl[c_hi];
    float p10 = rh[c_lo], p11 = rh[c_hi];

    const float4* wc = wb + ci * CO;
    #pragma unroll
    for (int co = 0; co < CO; co++) {
      float4 w4 = wc[co];                      // ds_read_b128, 2-addr broadcast
      acc[co] += w4.x*p00 + w4.y*p01 + w4.z*p10 + w4.w*p11;
    }
  }

  int pix = y*Hout + x;
  #pragma unroll
  for (int co = 0; co < CO; co++) {
    float v = acc[co];
    v = (v >= 0.f) ? v : 0.01f*v;
    out[((size_t)b*CO + co)*((size_t)Hout*Hout) + pix] = v;
  }
}

// ---------------- final: reflect-pad + 3x3 conv (16 -> 6) + tanh ----------------
__global__ void k_final(const float* __restrict__ in, float* __restrict__ out,
                        const float* __restrict__ w, const float* __restrict__ bias)
{
  int idx = blockIdx.x*blockDim.x + threadIdx.x;
  int total = 3 * HWP;
  if (idx >= total) return;
  int x = idx & (WWI-1);
  int y = (idx >> 9) & (HH-1);
  int b = idx / HWP;

  int ry[3], rx[3];
  #pragma unroll
  for (int d = 0; d < 3; d++) {
    int t = y - 1 + d;
    t = (t < 0) ? -t : t;
    ry[d] = (t >= HH) ? (2*(HH-1) - t) : t;
    t = x - 1 + d;
    t = (t < 0) ? -t : t;
    rx[d] = (t >= WWI) ? (2*(WWI-1) - t) : t;
  }

  float acc[6];
  #pragma unroll
  for (int co = 0; co < 6; co++) acc[co] = bias[co];

  for (int ci = 0; ci < 16; ci++) {
    const float* ib = in + ((size_t)(b*16) + ci) * HWP;
    float p[9];
    #pragma unroll
    for (int dy = 0; dy < 3; dy++)
      #pragma unroll
      for (int dx = 0; dx < 3; dx++)
        p[dy*3+dx] = ib[ry[dy]*WWI + rx[dx]];
    const float* wc = w + ci*9;
    #pragma unroll
    for (int co = 0; co < 6; co++) {
      const float* wcc = wc + co*16*9;
      #pragma unroll
      for (int k = 0; k < 9; k++) acc[co] += wcc[k] * p[k];
    }
  }

  int pix = y*WWI + x;
  #pragma unroll
  for (int co = 0; co < 6; co++)
    out[((size_t)(b*6) + co)*HWP + pix] = tanhf(acc[co]);
}

// ---------------- blending: fused grid-sample + weighting (all fp32) ----------------
__global__ void k_blend(const float* __restrict__ xin, const float* __restrict__ neighbors,
                        const int* __restrict__ aidx, const float* __restrict__ albedos,
                        const float* __restrict__ flows, float* __restrict__ out)
{
  int idx = blockIdx.x*blockDim.x + threadIdx.x;
  if (idx >= HWP) return;
  int xo = idx & (WWI-1);
  int yo = idx >> 9;

  float xv[9];
  #pragma unroll
  for (int i = 0; i < 9; i++) xv[i] = xin[i];

  float f0[6];
  #pragma unroll
  for (int c = 0; c < 6; c++) f0[c] = flows[(size_t)c*HWP + idx];

  const float* alb = albedos + (size_t)aidx[0]*3*HWP;
  float albp[3];
  #pragma unroll
  for (int ch = 0; ch < 3; ch++) albp[ch] = alb[(size_t)ch*HWP + idx];

  float num0 = 0.f, num1 = 0.f, num2 = 0.f;
  float wsum = 0.f;

  #pragma unroll
  for (int n = 0; n < 2; n++) {
    float dl = xv[0] - xv[(n+1)*3 + 0];
    float dv = xv[1] - xv[(n+1)*3 + 1];
    float dt = xv[2] - xv[(n+1)*3 + 2];
    bool fl = fabsf(dl) > 0.f;

    float ofx = dl*f0[0] + dv*f0[2] + dt*f0[4];
    float ofy = dl*f0[1] + dv*f0[3] + dt*f0[5];

    float gx = ((-1.f + (2.f/511.f)*(float)xo) + ofx + 1.f)*256.f - 0.5f;
    float gy = ((-1.f + (2.f/511.f)*(float)yo) + ofy + 1.f)*256.f - 0.5f;
    gx = fminf(fmaxf(gx, 0.f), 511.f);
    gy = fminf(fmaxf(gy, 0.f), 511.f);

    float x0f = floorf(gx), y0f = floorf(gy);
    float wx = gx - x0f, wy = gy - y0f;
    int x0i = (int)x0f, y0i = (int)y0f;
    int x1i = min(x0i + 1, WWI-1), y1i = min(y0i + 1, HH-1);

    float cw[4] = {(1.f-wx)*(1.f-wy), wx*(1.f-wy), (1.f-wx)*wy, wx*wy};
    int   cp[4] = {y0i*WWI + x0i, y0i*WWI + x1i, y1i*WWI + x0i, y1i*WWI + x1i};

    const float* nb = neighbors + (size_t)n*3*HWP;
    const float* Fn = flows + (size_t)(n+1)*6*HWP;

    float s0=0.f,s1=0.f,s2=0.f;
    float l0=0.f,l1=0.f,v0=0.f,v1=0.f,t0=0.f,t1=0.f;
    #pragma unroll
    for (int c = 0; c < 4; c++) {
      int p = cp[c];
      float ww = cw[c];
      float n0 = nb[p];
      float n1 = nb[HWP + p];
      float n2 = nb[2*HWP + p];
      if (fl) {
        n0 /= alb[p];
        n1 /= alb[HWP + p];
        n2 /= alb[2*HWP + p];
      }
      s0 += ww*n0; s1 += ww*n1; s2 += ww*n2;
      l0 += ww*Fn[p];             l1 += ww*Fn[HWP + p];
      v0 += ww*Fn[2*HWP + p];     v1 += ww*Fn[3*HWP + p];
      t0 += ww*Fn[4*HWP + p];     t1 += ww*Fn[5*HWP + p];
    }

    float wi0 = fl ? s0*albp[0] : s0;
    float wi1 = fl ? s1*albp[1] : s1;
    float wi2 = fl ? s2*albp[2] : s2;

    float obx = dl*l0 + dv*v0 + dt*t0;
    float oby = dl*l1 + dv*v1 + dt*t1;
    float dist = fabsf(ofx - obx) + fabsf(ofy - oby);
    float wgt = expf(-51.2f * dist);

    wsum += wgt;
    num0 += wgt*wi0; num1 += wgt*wi1; num2 += wgt*wi2;
  }

  float inv = 1.f / (wsum + 1e-5f);
  out[idx]         = num0*inv;
  out[HWP + idx]   = num1*inv;
  out[2*HWP + idx] = num2*inv;
}

// ---------------- launch ----------------
extern "C" void kernel_launch(void* const* d_in, const int* in_sizes, int n_in,
                              void* d_out, int out_size, void* d_ws, size_t ws_size,
                              hipStream_t stream) {
  const float* x         = (const float*)d_in[0];
  const float* neighbors = (const float*)d_in[1];
  const int*   aidx      = (const int*)d_in[2];
  const float* wts[10];
  const float* bis[10];
  for (int i = 0; i < 9; i++) { wts[i] = (const float*)d_in[3+2*i]; bis[i] = (const float*)d_in[4+2*i]; }
  wts[9] = (const float*)d_in[21];   // wf
  bis[9] = (const float*)d_in[22];   // bf
  const float* albedos = (const float*)d_in[23];

  float* wk   = (float*)d_ws;
  float* bufS = wk;                   // 792 floats (layer0 out)
  float* bufA = wk + 800;             // up to 4,718,592 floats
  float* bufB = bufA + 4718592;       // up to 12,582,912 floats
  size_t need = (size_t)(800 + 4718592 + 12582912) * 4;
  if (ws_size < need) return;

  // Folded-weight buffers live in bufA slack [3,200,000, 3,216,384):
  // above L7's peak use (3,145,728 floats) and only overwritten by k_final
  // (4,718,592 floats) AFTER L8 has consumed them. No workspace growth.
  float* wf6 = bufA + 3200000;            // 16*32*16 = 8192 floats
  float* wf7 = wf6 + 8192;                // 16*16*16 = 4096 floats
  float* wf8 = wf7 + 4096;                // 16*16*16 = 4096 floats
  k_foldw3<<<4, 256, 0, stream>>>(wts[6], wts[7], wts[8], wf6, wf7, wf8);

  k_layer0<<<1, 256, 0, stream>>>(x, wts[0], bis[0], bufS);

  auto spanOf = [](int Hin, int TR) { int s = TR/2 + 2; return (s > Hin) ? Hin : s; };
  auto ldsB = [&](int COB, int Cin, int Hin, int TR) {
    return (size_t)(COB*Cin*9 + COB + Cin*spanOf(Hin,TR)*Hin) * 4;
  };

  // L1: Cin=66 CO=64 Hin=2  | COB=16 TR=4 G=1 | blocks 3*4*1=12
  k_conv_lds<1><<<12, 256, ldsB(16,66,2,4), stream>>>(bufS, bufA, wts[1], bis[1],
                                                      3, 66, 64, 16, 2, 4, spanOf(2,4));
  // L2: Cin=64 CO=64 Hin=4  | COB=8 TR=8 G=1 | blocks 3*8*1=24
  k_conv_lds<1><<<24, 256, ldsB(8,64,4,8), stream>>>(bufA, bufB, wts[2], bis[2],
                                                     3, 64, 64, 8, 4, 8, spanOf(4,8));
  // L3: Cin=64 CO=32 Hin=8  | COB=4 TR=16 G=2 | blocks 3*8*1=24
  k_conv_lds<2><<<24, 256, ldsB(4,64,8,16), stream>>>(bufB, bufA, wts[3], bis[3],
                                                      3, 64, 32, 4, 8, 16, spanOf(8,16));
  // L4: Cin=32 CO=32 Hin=16 | COB=8 TR=8 G=2 | blocks 3*4*4=48
  k_conv_lds<2><<<48, 256, ldsB(8,32,16,8), stream>>>(bufA, bufB, wts[4], bis[4],
                                                      3, 32, 32, 8, 16, 8, spanOf(16,8));
  // L5: Cin=32 CO=32 Hin=32 | COB=8 TR=8 G=4 | blocks 3*4*8=96
  k_conv_lds<4><<<96, 256, ldsB(8,32,32,8), stream>>>(bufB, bufA, wts[5], bis[5],
                                                      3, 32, 32, 8, 32, 8, spanOf(32,8));

  auto blocks = [](int total){ return (total + 255) / 256; };
  // L6-L8: LDS-weight parity upconv, one thread per output pixel.
  // Dynamic LDS = 4 parities * Cin * CO * 16 B.
  k_upconv_w<16><<<blocks(3*128*128), 256, (size_t)4*32*16*16, stream>>>(bufA, bufB, wf6, bis[6], 3, 32, 64);
  k_upconv_w<16><<<blocks(3*256*256), 256, (size_t)4*16*16*16, stream>>>(bufB, bufA, wf7, bis[7], 3, 16, 128);
  k_upconv_w<16><<<blocks(3*512*512), 256, (size_t)4*16*16*16, stream>>>(bufA, bufB, wf8, bis[8], 3, 16, 256);

  k_final<<<blocks(3*HWP), 256, 0, stream>>>(bufB, bufA, wts[9], bis[9]);
  k_blend<<<blocks(HWP), 256, 0, stream>>>(x, neighbors, aidx, albedos, bufA, (float*)d_out);
}

// Round 8
// 451.819 us; speedup vs baseline: 1.2377x; 1.0184x over previous
//
#include <hip/hip_runtime.h>
#include <hip/hip_bf16.h>
#include <math.h>

// All inputs and the output are FLOAT32 (reference dtype). The "bf16" in the
// harness label is a literal string, not a dtype indicator.
//
// Upconv history:
//  R1/R3/R4: multi-output quad kernels (acc[4][*]) spill (excess WRITE_SIZE tell).
//  R5: per-lane weight addresses -> vector L1 traffic -> slow.
//  R6: s_load-uniform weights -> L6 latency-bound on tiny grid.
//  R7: LDS weights, thread-per-output: 62.8us L8 BUT 1.5e7 bank conflicts —
//    parity blocks were Cin*CO*16 B apart (4096 ≡ 0 mod 128B) -> px=0/px=1
//    addresses hit the SAME 4 banks.
//  Now: (a) pad parity stride +1 float4 (4112 B -> bank offset 4, disjoint);
//    (b) L7/L8 pair outputs (x, x+Hout/2): same (py,px) parity -> one ds_read
//    feeds 8 FMAs (2 outputs), halving per-output LDS ops. acc[2][16]+8 px
//    ~= R6-p2's proven 56-VGPR no-spill footprint.

#define HH 512
#define WWI 512
#define HWP (HH*WWI)

// ---------------- layer 0: 1x1 conv on upsampled 2x2 + leakyrelu + coordconv ----------------
__global__ void k_layer0(const float* __restrict__ xin, const float* __restrict__ w,
                         const float* __restrict__ bias, float* __restrict__ out)
{
  for (int idx = threadIdx.x; idx < 3*66*4; idx += blockDim.x) {
    int pos = idx & 3;
    int c = (idx >> 2) % 66;
    int b = idx / (66*4);
    float v;
    if (c < 64) {
      float a = bias[c];
      #pragma unroll
      for (int ci = 0; ci < 3; ci++) a += w[c*3+ci] * xin[b*3+ci];
      v = (a >= 0.f) ? a : 0.01f*a;
    } else {
      int xx = pos & 1, yy = pos >> 1;
      v = (c == 64) ? 2.f*(float)xx : 2.f*(float)yy;
    }
    out[idx] = v;
  }
}

__device__ __forceinline__ int refl_up(int t, int n) {
  t = (t < 0) ? -t : t;
  t = (t >= n) ? (2*(n-1) - t) : t;
  return t >> 1;
}

// ---------------- LDS conv: upsample x2 + reflect-pad + 3x3 + leakyrelu ----------------
template<int G>
__global__ void k_conv_lds(const float* __restrict__ in, float* __restrict__ out,
                           const float* __restrict__ w, const float* __restrict__ bias,
                           int B, int Cin, int CO, int COB, int Hin, int TR, int SPAN)
{
  extern __shared__ float lds[];
  const int Hout = Hin * 2;
  const int rowTiles = Hout / TR;
  const int coTiles = CO / COB;
  int bid = blockIdx.x;
  int tile = bid % rowTiles;
  int cot  = (bid / rowTiles) % coTiles;
  int b    = bid / (rowTiles * coTiles);
  int tr0  = tile * TR;
  int co_base = cot * COB;

  int r0 = tr0/2 - 1;
  if (r0 < 0) r0 = 0;
  if (r0 > Hin - SPAN) r0 = Hin - SPAN;

  float* wlds = lds;                    // COB*Cin*9
  float* blds = wlds + COB*Cin*9;       // COB
  float* ilds = blds + COB;             // Cin*SPAN*Hin

  int nt = blockDim.x, tid = threadIdx.x;

  const float* wsrc = w + (size_t)co_base*Cin*9;
  for (int i = tid; i < COB*Cin*9; i += nt) wlds[i] = wsrc[i];
  for (int i = tid; i < COB; i += nt) blds[i] = bias[co_base + i];
  int icount = Cin*SPAN*Hin;
  for (int i = tid; i < icount; i += nt) {
    int col = i % Hin;
    int r = (i / Hin) % SPAN;
    int ci = i / (Hin*SPAN);
    ilds[i] = in[(((size_t)b*Cin + ci)*Hin + (r0 + r))*Hin + col];
  }
  __syncthreads();

  int npix = TR * Hout;
  int ngr = COB / G;
  int items = ngr * npix;
  for (int it = tid; it < items; it += nt) {
    int pix = it % npix;
    int cg = it / npix;
    int x = pix % Hout;
    int y = tr0 + pix / Hout;

    int ry[3], rx[3];
    #pragma unroll
    for (int d = 0; d < 3; d++) {
      int s = refl_up(y - 1 + d, Hout) - r0;
      s = (s < 0) ? 0 : s;
      s = (s > SPAN-1) ? SPAN-1 : s;
      ry[d] = s;
      rx[d] = refl_up(x - 1 + d, Hout);
    }

    float acc[G];
    #pragma unroll
    for (int j = 0; j < G; j++) acc[j] = blds[cg*G + j];

    for (int ci = 0; ci < Cin; ci++) {
      const float* ib = ilds + (size_t)ci*SPAN*Hin;
      float p[9];
      #pragma unroll
      for (int dy = 0; dy < 3; dy++)
        #pragma unroll
        for (int dx = 0; dx < 3; dx++)
          p[dy*3+dx] = ib[ry[dy]*Hin + rx[dx]];
      const float* wc = wlds + ((size_t)(cg*G)*Cin + ci)*9;
      #pragma unroll
      for (int j = 0; j < G; j++) {
        #pragma unroll
        for (int k = 0; k < 9; k++) acc[j] += wc[(size_t)j*Cin*9 + k] * p[k];
      }
    }

    #pragma unroll
    for (int j = 0; j < G; j++) {
      float v = acc[j];
      v = (v >= 0.f) ? v : 0.01f*v;
      out[(((size_t)b*CO + co_base + cg*G + j)*Hout + y)*Hout + x] = v;
    }
  }
}

// ---------------- weight folding for upsample-conv parity decomposition ----------------
// Folded layout: f[((co*Cin + ci)*16) + p*4 + ky*2 + kx], p = py*2+px. 16B float4 per p.
__global__ void k_foldw3(const float* __restrict__ w6, const float* __restrict__ w7,
                         const float* __restrict__ w8, float* __restrict__ f6,
                         float* __restrict__ f7, float* __restrict__ f8)
{
  int idx = blockIdx.x*blockDim.x + threadIdx.x;
  const float* w; float* f; int n;
  if (idx < 512)       { w = w6; f = f6; n = idx; }        // CO=16, Cin=32
  else if (idx < 768)  { w = w7; f = f7; n = idx - 512; }  // CO=16, Cin=16
  else if (idx < 1024) { w = w8; f = f8; n = idx - 768; }  // CO=16, Cin=16
  else return;

  const float* ws = w + (size_t)n*9;
  float W[9];
  #pragma unroll
  for (int k = 0; k < 9; k++) W[k] = ws[k];

  float a[2][2][3];
  #pragma unroll
  for (int c = 0; c < 3; c++) {
    a[0][0][c] = W[c];          a[0][1][c] = W[3+c] + W[6+c];
    a[1][0][c] = W[c] + W[3+c]; a[1][1][c] = W[6+c];
  }
  float* fo = f + (size_t)n*16;
  #pragma unroll
  for (int py = 0; py < 2; py++)
    #pragma unroll
    for (int px = 0; px < 2; px++) {
      int p = py*2 + px;
      #pragma unroll
      for (int ky = 0; ky < 2; ky++) {
        float kx0 = (px == 0) ? a[py][ky][0] : (a[py][ky][0] + a[py][ky][1]);
        float kx1 = (px == 0) ? (a[py][ky][1] + a[py][ky][2]) : a[py][ky][2];
        fo[p*4 + ky*2 + 0] = kx0;
        fo[p*4 + ky*2 + 1] = kx1;
      }
    }
}

// ---------------- LDS-weight parity upconv: one thread per OUTPUT pixel ----------------
// Parity blocks padded by +1 float4 so px=0/px=1 reads hit disjoint banks.
template<int CO>
__global__ void k_upconv_w(const float* __restrict__ in, float* __restrict__ out,
                           const float* __restrict__ wfold, const float* __restrict__ bias,
                           int B, int Cin, int Hin)
{
  extern __shared__ float4 wlds4[];           // [4][Cin*CO + 1]
  int nt = blockDim.x, tid = threadIdx.x;
  int stride = Cin * CO + 1;                  // +1 float4 pad: bank-offset 4 between parities
  int nw = Cin * CO * 4;
  const float4* wsrc = reinterpret_cast<const float4*>(wfold);
  for (int s = tid; s < nw; s += nt) {
    int p = s & 3;
    int r = s >> 2;            // co*Cin + ci
    int ci = r % Cin;
    int co = r / Cin;
    wlds4[p*stride + ci*CO + co] = wsrc[s];
  }
  __syncthreads();

  int Hout = Hin * 2;
  int total = B * Hout * Hout;
  int idx = blockIdx.x*nt + tid;
  if (idx >= total) return;
  int x = idx % Hout;
  int y = (idx / Hout) % Hout;
  int b = idx / (Hout * Hout);

  int X = x >> 1, Y = y >> 1;
  int px = x & 1, py = y & 1;

  int r_lo = py ? Y : (Y > 0 ? Y-1 : 0);
  int r_hi = py ? (Y < Hin-1 ? Y+1 : Hin-1) : Y;
  int c_lo = px ? X : (X > 0 ? X-1 : 0);
  int c_hi = px ? (X < Hin-1 ? X+1 : Hin-1) : X;

  float acc[CO];
  #pragma unroll
  for (int co = 0; co < CO; co++) acc[co] = bias[co];

  const size_t plane = (size_t)Hin * Hin;
  const float* ibase = in + (size_t)b * Cin * plane;
  const float4* wb = wlds4 + (py*2 + px) * stride;

  for (int ci = 0; ci < Cin; ci++) {
    const float* ip = ibase + (size_t)ci * plane;
    const float* rl = ip + (size_t)r_lo * Hin;
    const float* rh = ip + (size_t)r_hi * Hin;
    float p00 = rl[c_lo], p01 = rl[c_hi];
    float p10 = rh[c_lo], p11 = rh[c_hi];

    const float4* wc = wb + ci * CO;
    #pragma unroll
    for (int co = 0; co < CO; co++) {
      float4 w4 = wc[co];
      acc[co] += w4.x*p00 + w4.y*p01 + w4.z*p10 + w4.w*p11;
    }
  }

  int pix = y*Hout + x;
  #pragma unroll
  for (int co = 0; co < CO; co++) {
    float v = acc[co];
    v = (v >= 0.f) ? v : 0.01f*v;
    out[((size_t)b*CO + co)*((size_t)Hout*Hout) + pix] = v;
  }
}

// ---------------- paired LDS-weight upconv: one thread = outputs (x, x+Hout/2) ----------
// Both outputs share (py,px) parity -> one ds_read_b128 feeds 8 FMAs.
// acc[2][CO] = 32 regs + 8 pixels: R6-p2's proven 56-VGPR no-spill footprint.
template<int CO>
__global__ void k_upconv_w2(const float* __restrict__ in, float* __restrict__ out,
                            const float* __restrict__ wfold, const float* __restrict__ bias,
                            int B, int Cin, int Hin)
{
  extern __shared__ float4 wlds4[];           // [4][Cin*CO + 1]
  int nt = blockDim.x, tid = threadIdx.x;
  int stride = Cin * CO + 1;
  int nw = Cin * CO * 4;
  const float4* wsrc = reinterpret_cast<const float4*>(wfold);
  for (int s = tid; s < nw; s += nt) {
    int p = s & 3;
    int r = s >> 2;
    int ci = r % Cin;
    int co = r / Cin;
    wlds4[p*stride + ci*CO + co] = wsrc[s];
  }
  __syncthreads();

  int Hout = Hin * 2;
  int half = Hout >> 1;                       // even -> x and x+half share px parity
  int total = B * Hout * half;
  int idx = blockIdx.x*nt + tid;
  if (idx >= total) return;
  int x1 = idx % half;
  int y  = (idx / half) % Hout;
  int b  = idx / (half * Hout);

  int px = x1 & 1, py = y & 1;
  int X1 = x1 >> 1, Y = y >> 1;
  int X2 = X1 + (Hin >> 1);                   // (x1+half)>>1

  int r_lo = py ? Y : (Y > 0 ? Y-1 : 0);
  int r_hi = py ? (Y < Hin-1 ? Y+1 : Hin-1) : Y;
  int c1lo = px ? X1 : (X1 > 0 ? X1-1 : 0);
  int c1hi = px ? (X1 < Hin-1 ? X1+1 : Hin-1) : X1;
  int c2lo = px ? X2 : (X2 > 0 ? X2-1 : 0);
  int c2hi = px ? (X2 < Hin-1 ? X2+1 : Hin-1) : X2;

  float acc0[CO], acc1[CO];
  #pragma unroll
  for (int co = 0; co < CO; co++) { float bv = bias[co]; acc0[co] = bv; acc1[co] = bv; }

  const size_t plane = (size_t)Hin * Hin;
  const float* ibase = in + (size_t)b * Cin * plane;
  const float4* wb = wlds4 + (py*2 + px) * stride;

  for (int ci = 0; ci < Cin; ci++) {
    const float* ip = ibase + (size_t)ci * plane;
    const float* rl = ip + (size_t)r_lo * Hin;
    const float* rh = ip + (size_t)r_hi * Hin;
    float a0 = rl[c1lo], a1 = rl[c1hi];
    float a2 = rh[c1lo], a3 = rh[c1hi];
    float b0 = rl[c2lo], b1 = rl[c2hi];
    float b2 = rh[c2lo], b3 = rh[c2hi];

    const float4* wc = wb + ci * CO;
    #pragma unroll
    for (int co = 0; co < CO; co++) {
      float4 w4 = wc[co];
      acc0[co] += w4.x*a0 + w4.y*a1 + w4.z*a2 + w4.w*a3;
      acc1[co] += w4.x*b0 + w4.y*b1 + w4.z*b2 + w4.w*b3;
    }
  }

  size_t oplane = (size_t)Hout * Hout;
  size_t pix1 = (size_t)y*Hout + x1;
  float* obase = out + (size_t)b * CO * oplane;
  #pragma unroll
  for (int co = 0; co < CO; co++) {
    float v0 = acc0[co]; v0 = (v0 >= 0.f) ? v0 : 0.01f*v0;
    float v1 = acc1[co]; v1 = (v1 >= 0.f) ? v1 : 0.01f*v1;
    float* op = obase + (size_t)co * oplane;
    op[pix1] = v0;
    op[pix1 + half] = v1;
  }
}

// ---------------- final: reflect-pad + 3x3 conv (16 -> 6) + tanh ----------------
__global__ void k_final(const float* __restrict__ in, float* __restrict__ out,
                        const float* __restrict__ w, const float* __restrict__ bias)
{
  int idx = blockIdx.x*blockDim.x + threadIdx.x;
  int total = 3 * HWP;
  if (idx >= total) return;
  int x = idx & (WWI-1);
  int y = (idx >> 9) & (HH-1);
  int b = idx / HWP;

  int ry[3], rx[3];
  #pragma unroll
  for (int d = 0; d < 3; d++) {
    int t = y - 1 + d;
    t = (t < 0) ? -t : t;
    ry[d] = (t >= HH) ? (2*(HH-1) - t) : t;
    t = x - 1 + d;
    t = (t < 0) ? -t : t;
    rx[d] = (t >= WWI) ? (2*(WWI-1) - t) : t;
  }

  float acc[6];
  #pragma unroll
  for (int co = 0; co < 6; co++) acc[co] = bias[co];

  for (int ci = 0; ci < 16; ci++) {
    const float* ib = in + ((size_t)(b*16) + ci) * HWP;
    float p[9];
    #pragma unroll
    for (int dy = 0; dy < 3; dy++)
      #pragma unroll
      for (int dx = 0; dx < 3; dx++)
        p[dy*3+dx] = ib[ry[dy]*WWI + rx[dx]];
    const float* wc = w + ci*9;
    #pragma unroll
    for (int co = 0; co < 6; co++) {
      const float* wcc = wc + co*16*9;
      #pragma unroll
      for (int k = 0; k < 9; k++) acc[co] += wcc[k] * p[k];
    }
  }

  int pix = y*WWI + x;
  #pragma unroll
  for (int co = 0; co < 6; co++)
    out[((size_t)(b*6) + co)*HWP + pix] = tanhf(acc[co]);
}

// ---------------- blending: fused grid-sample + weighting (all fp32) ----------------
__global__ void k_blend(const float* __restrict__ xin, const float* __restrict__ neighbors,
                        const int* __restrict__ aidx, const float* __restrict__ albedos,
                        const float* __restrict__ flows, float* __restrict__ out)
{
  int idx = blockIdx.x*blockDim.x + threadIdx.x;
  if (idx >= HWP) return;
  int xo = idx & (WWI-1);
  int yo = idx >> 9;

  float xv[9];
  #pragma unroll
  for (int i = 0; i < 9; i++) xv[i] = xin[i];

  float f0[6];
  #pragma unroll
  for (int c = 0; c < 6; c++) f0[c] = flows[(size_t)c*HWP + idx];

  const float* alb = albedos + (size_t)aidx[0]*3*HWP;
  float albp[3];
  #pragma unroll
  for (int ch = 0; ch < 3; ch++) albp[ch] = alb[(size_t)ch*HWP + idx];

  float num0 = 0.f, num1 = 0.f, num2 = 0.f;
  float wsum = 0.f;

  #pragma unroll
  for (int n = 0; n < 2; n++) {
    float dl = xv[0] - xv[(n+1)*3 + 0];
    float dv = xv[1] - xv[(n+1)*3 + 1];
    float dt = xv[2] - xv[(n+1)*3 + 2];
    bool fl = fabsf(dl) > 0.f;

    float ofx = dl*f0[0] + dv*f0[2] + dt*f0[4];
    float ofy = dl*f0[1] + dv*f0[3] + dt*f0[5];

    float gx = ((-1.f + (2.f/511.f)*(float)xo) + ofx + 1.f)*256.f - 0.5f;
    float gy = ((-1.f + (2.f/511.f)*(float)yo) + ofy + 1.f)*256.f - 0.5f;
    gx = fminf(fmaxf(gx, 0.f), 511.f);
    gy = fminf(fmaxf(gy, 0.f), 511.f);

    float x0f = floorf(gx), y0f = floorf(gy);
    float wx = gx - x0f, wy = gy - y0f;
    int x0i = (int)x0f, y0i = (int)y0f;
    int x1i = min(x0i + 1, WWI-1), y1i = min(y0i + 1, HH-1);

    float cw[4] = {(1.f-wx)*(1.f-wy), wx*(1.f-wy), (1.f-wx)*wy, wx*wy};
    int   cp[4] = {y0i*WWI + x0i, y0i*WWI + x1i, y1i*WWI + x0i, y1i*WWI + x1i};

    const float* nb = neighbors + (size_t)n*3*HWP;
    const float* Fn = flows + (size_t)(n+1)*6*HWP;

    float s0=0.f,s1=0.f,s2=0.f;
    float l0=0.f,l1=0.f,v0=0.f,v1=0.f,t0=0.f,t1=0.f;
    #pragma unroll
    for (int c = 0; c < 4; c++) {
      int p = cp[c];
      float ww = cw[c];
      float n0 = nb[p];
      float n1 = nb[HWP + p];
      float n2 = nb[2*HWP + p];
      if (fl) {
        n0 /= alb[p];
        n1 /= alb[HWP + p];
        n2 /= alb[2*HWP + p];
      }
      s0 += ww*n0; s1 += ww*n1; s2 += ww*n2;
      l0 += ww*Fn[p];             l1 += ww*Fn[HWP + p];
      v0 += ww*Fn[2*HWP + p];     v1 += ww*Fn[3*HWP + p];
      t0 += ww*Fn[4*HWP + p];     t1 += ww*Fn[5*HWP + p];
    }

    float wi0 = fl ? s0*albp[0] : s0;
    float wi1 = fl ? s1*albp[1] : s1;
    float wi2 = fl ? s2*albp[2] : s2;

    float obx = dl*l0 + dv*v0 + dt*t0;
    float oby = dl*l1 + dv*v1 + dt*t1;
    float dist = fabsf(ofx - obx) + fabsf(ofy - oby);
    float wgt = expf(-51.2f * dist);

    wsum += wgt;
    num0 += wgt*wi0; num1 += wgt*wi1; num2 += wgt*wi2;
  }

  float inv = 1.f / (wsum + 1e-5f);
  out[idx]         = num0*inv;
  out[HWP + idx]   = num1*inv;
  out[2*HWP + idx] = num2*inv;
}

// ---------------- launch ----------------
extern "C" void kernel_launch(void* const* d_in, const int* in_sizes, int n_in,
                              void* d_out, int out_size, void* d_ws, size_t ws_size,
                              hipStream_t stream) {
  const float* x         = (const float*)d_in[0];
  const float* neighbors = (const float*)d_in[1];
  const int*   aidx      = (const int*)d_in[2];
  const float* wts[10];
  const float* bis[10];
  for (int i = 0; i < 9; i++) { wts[i] = (const float*)d_in[3+2*i]; bis[i] = (const float*)d_in[4+2*i]; }
  wts[9] = (const float*)d_in[21];   // wf
  bis[9] = (const float*)d_in[22];   // bf
  const float* albedos = (const float*)d_in[23];

  float* wk   = (float*)d_ws;
  float* bufS = wk;                   // 792 floats (layer0 out)
  float* bufA = wk + 800;             // up to 4,718,592 floats
  float* bufB = bufA + 4718592;       // up to 12,582,912 floats
  size_t need = (size_t)(800 + 4718592 + 12582912) * 4;
  if (ws_size < need) return;

  // Folded-weight buffers live in bufA slack [3,200,000, 3,216,384):
  // above L7's peak use (3,145,728 floats) and only overwritten by k_final
  // (4,718,592 floats) AFTER L8 has consumed them. No workspace growth.
  float* wf6 = bufA + 3200000;            // 16*32*16 = 8192 floats
  float* wf7 = wf6 + 8192;                // 16*16*16 = 4096 floats
  float* wf8 = wf7 + 4096;                // 16*16*16 = 4096 floats
  k_foldw3<<<4, 256, 0, stream>>>(wts[6], wts[7], wts[8], wf6, wf7, wf8);

  k_layer0<<<1, 256, 0, stream>>>(x, wts[0], bis[0], bufS);

  auto spanOf = [](int Hin, int TR) { int s = TR/2 + 2; return (s > Hin) ? Hin : s; };
  auto ldsB = [&](int COB, int Cin, int Hin, int TR) {
    return (size_t)(COB*Cin*9 + COB + Cin*spanOf(Hin,TR)*Hin) * 4;
  };

  // L1: Cin=66 CO=64 Hin=2  | COB=16 TR=4 G=1 | blocks 3*4*1=12
  k_conv_lds<1><<<12, 256, ldsB(16,66,2,4), stream>>>(bufS, bufA, wts[1], bis[1],
                                                      3, 66, 64, 16, 2, 4, spanOf(2,4));
  // L2: Cin=64 CO=64 Hin=4  | COB=8 TR=8 G=1 | blocks 3*8*1=24
  k_conv_lds<1><<<24, 256, ldsB(8,64,4,8), stream>>>(bufA, bufB, wts[2], bis[2],
                                                     3, 64, 64, 8, 4, 8, spanOf(4,8));
  // L3: Cin=64 CO=32 Hin=8  | COB=4 TR=16 G=2 | blocks 3*8*1=24
  k_conv_lds<2><<<24, 256, ldsB(4,64,8,16), stream>>>(bufB, bufA, wts[3], bis[3],
                                                      3, 64, 32, 4, 8, 16, spanOf(8,16));
  // L4: Cin=32 CO=32 Hin=16 | COB=8 TR=8 G=2 | blocks 3*4*4=48
  k_conv_lds<2><<<48, 256, ldsB(8,32,16,8), stream>>>(bufA, bufB, wts[4], bis[4],
                                                      3, 32, 32, 8, 16, 8, spanOf(16,8));
  // L5: Cin=32 CO=32 Hin=32 | COB=8 TR=8 G=4 | blocks 3*4*8=96
  k_conv_lds<4><<<96, 256, ldsB(8,32,32,8), stream>>>(bufB, bufA, wts[5], bis[5],
                                                      3, 32, 32, 8, 32, 8, spanOf(32,8));

  auto blocks = [](int total){ return (total + 255) / 256; };
  // LDS bytes: 4 parity blocks * (Cin*CO + 1 pad) float4s * 16 B.
  // L6: thread-per-output (grid too small to pair), padded weights.
  k_upconv_w<16><<<blocks(3*128*128), 256, (size_t)4*(32*16+1)*16, stream>>>(bufA, bufB, wf6, bis[6], 3, 32, 64);
  // L7/L8: paired outputs (x, x+Hout/2) -> 1 ds_read per 8 FMAs.
  k_upconv_w2<16><<<blocks(3*256*128), 256, (size_t)4*(16*16+1)*16, stream>>>(bufB, bufA, wf7, bis[7], 3, 16, 128);
  k_upconv_w2<16><<<blocks(3*512*256), 256, (size_t)4*(16*16+1)*16, stream>>>(bufA, bufB, wf8, bis[8], 3, 16, 256);

  k_final<<<blocks(3*HWP), 256, 0, stream>>>(bufB, bufA, wts[9], bis[9]);
  k_blend<<<blocks(HWP), 256, 0, stream>>>(x, neighbors, aidx, albedos, bufA, (float*)d_out);
}

// Round 9
// 332.228 us; speedup vs baseline: 1.6832x; 1.3600x over previous
//
#include <hip/hip_runtime.h>
#include <hip/hip_bf16.h>
#include <math.h>

// All inputs and the output are FLOAT32 (reference dtype). The "bf16" in the
// harness label is a literal string, not a dtype indicator.
//
// Upconv history:
//  R1/R3/R4: multi-output quad kernels spill (excess WRITE_SIZE tell).
//  R5: per-lane weight addresses -> vector L1 traffic -> slow.
//  R6: s_load-uniform weights -> latency-bound serial s_load chains on tiny grids.
//  R7: LDS weights + thread-per-output: fast, but parity blocks 4096B apart ->
//      same-bank 2-addr reads, 1.5e7 conflicts. R8: +1-float4 pad + paired
//      outputs fixed upconv (L6-L8 all < 30us now).
//  R8 profile: L5 conv_lds = 64us top kernel. Occ 3.9%, VALU 10% -> the early
//      decoder (L1-L5) is latency-bound: tiny grids (12-96 blocks) x ~5800-op
//      serial per-thread chains. Budget says L1-L4 similar (~280us combined).
//  Now: parity-fold EVERYTHING. k_upconv_s = one thread per output scalar,
//      blockIdx.y = co, per-co folded weights in LDS (2-4KB, parity-padded).
//      L3: 96 blocks, L4: 384, L5: 1536. L1/L2 keep conv_lds with finer
//      co-tiles (48/96 blocks).

#define HH 512
#define WWI 512
#define HWP (HH*WWI)

// ---------------- layer 0: 1x1 conv on upsampled 2x2 + leakyrelu + coordconv ----------------
__global__ void k_layer0(const float* __restrict__ xin, const float* __restrict__ w,
                         const float* __restrict__ bias, float* __restrict__ out)
{
  for (int idx = threadIdx.x; idx < 3*66*4; idx += blockDim.x) {
    int pos = idx & 3;
    int c = (idx >> 2) % 66;
    int b = idx / (66*4);
    float v;
    if (c < 64) {
      float a = bias[c];
      #pragma unroll
      for (int ci = 0; ci < 3; ci++) a += w[c*3+ci] * xin[b*3+ci];
      v = (a >= 0.f) ? a : 0.01f*a;
    } else {
      int xx = pos & 1, yy = pos >> 1;
      v = (c == 64) ? 2.f*(float)xx : 2.f*(float)yy;
    }
    out[idx] = v;
  }
}

__device__ __forceinline__ int refl_up(int t, int n) {
  t = (t < 0) ? -t : t;
  t = (t >= n) ? (2*(n-1) - t) : t;
  return t >> 1;
}

// ---------------- LDS conv: upsample x2 + reflect-pad + 3x3 + leakyrelu ----------------
template<int G>
__global__ void k_conv_lds(const float* __restrict__ in, float* __restrict__ out,
                           const float* __restrict__ w, const float* __restrict__ bias,
                           int B, int Cin, int CO, int COB, int Hin, int TR, int SPAN)
{
  extern __shared__ float lds[];
  const int Hout = Hin * 2;
  const int rowTiles = Hout / TR;
  const int coTiles = CO / COB;
  int bid = blockIdx.x;
  int tile = bid % rowTiles;
  int cot  = (bid / rowTiles) % coTiles;
  int b    = bid / (rowTiles * coTiles);
  int tr0  = tile * TR;
  int co_base = cot * COB;

  int r0 = tr0/2 - 1;
  if (r0 < 0) r0 = 0;
  if (r0 > Hin - SPAN) r0 = Hin - SPAN;

  float* wlds = lds;                    // COB*Cin*9
  float* blds = wlds + COB*Cin*9;       // COB
  float* ilds = blds + COB;             // Cin*SPAN*Hin

  int nt = blockDim.x, tid = threadIdx.x;

  const float* wsrc = w + (size_t)co_base*Cin*9;
  for (int i = tid; i < COB*Cin*9; i += nt) wlds[i] = wsrc[i];
  for (int i = tid; i < COB; i += nt) blds[i] = bias[co_base + i];
  int icount = Cin*SPAN*Hin;
  for (int i = tid; i < icount; i += nt) {
    int col = i % Hin;
    int r = (i / Hin) % SPAN;
    int ci = i / (Hin*SPAN);
    ilds[i] = in[(((size_t)b*Cin + ci)*Hin + (r0 + r))*Hin + col];
  }
  __syncthreads();

  int npix = TR * Hout;
  int ngr = COB / G;
  int items = ngr * npix;
  for (int it = tid; it < items; it += nt) {
    int pix = it % npix;
    int cg = it / npix;
    int x = pix % Hout;
    int y = tr0 + pix / Hout;

    int ry[3], rx[3];
    #pragma unroll
    for (int d = 0; d < 3; d++) {
      int s = refl_up(y - 1 + d, Hout) - r0;
      s = (s < 0) ? 0 : s;
      s = (s > SPAN-1) ? SPAN-1 : s;
      ry[d] = s;
      rx[d] = refl_up(x - 1 + d, Hout);
    }

    float acc[G];
    #pragma unroll
    for (int j = 0; j < G; j++) acc[j] = blds[cg*G + j];

    for (int ci = 0; ci < Cin; ci++) {
      const float* ib = ilds + (size_t)ci*SPAN*Hin;
      float p[9];
      #pragma unroll
      for (int dy = 0; dy < 3; dy++)
        #pragma unroll
        for (int dx = 0; dx < 3; dx++)
          p[dy*3+dx] = ib[ry[dy]*Hin + rx[dx]];
      const float* wc = wlds + ((size_t)(cg*G)*Cin + ci)*9;
      #pragma unroll
      for (int j = 0; j < G; j++) {
        #pragma unroll
        for (int k = 0; k < 9; k++) acc[j] += wc[(size_t)j*Cin*9 + k] * p[k];
      }
    }

    #pragma unroll
    for (int j = 0; j < G; j++) {
      float v = acc[j];
      v = (v >= 0.f) ? v : 0.01f*v;
      out[(((size_t)b*CO + co_base + cg*G + j)*Hout + y)*Hout + x] = v;
    }
  }
}

// ---------------- weight folding for upsample-conv parity decomposition ----------------
// upsample x2 + reflect-pad + 3x3 VALID conv == per-output-parity 2x2 conv on the
// ORIGINAL image. Verified for all Hin >= 2 incl. border clamps.
// Folded layout: f[((co*Cin + ci)*16) + p*4 + ky*2 + kx], p = py*2+px.
__global__ void k_foldw6(const float* __restrict__ w3, const float* __restrict__ w4,
                         const float* __restrict__ w5, const float* __restrict__ w6,
                         const float* __restrict__ w7, const float* __restrict__ w8,
                         float* __restrict__ f3, float* __restrict__ f4,
                         float* __restrict__ f5, float* __restrict__ f6,
                         float* __restrict__ f7, float* __restrict__ f8)
{
  int idx = blockIdx.x*blockDim.x + threadIdx.x;
  const float* w; float* f; int n;
  if      (idx < 2048) { w = w3; f = f3; n = idx; }         // L3: CO=32,Cin=64
  else if (idx < 3072) { w = w4; f = f4; n = idx - 2048; }  // L4: 32x32
  else if (idx < 4096) { w = w5; f = f5; n = idx - 3072; }  // L5: 32x32
  else if (idx < 4608) { w = w6; f = f6; n = idx - 4096; }  // L6: 16x32
  else if (idx < 4864) { w = w7; f = f7; n = idx - 4608; }  // L7: 16x16
  else if (idx < 5120) { w = w8; f = f8; n = idx - 4864; }  // L8: 16x16
  else return;

  const float* ws = w + (size_t)n*9;
  float W[9];
  #pragma unroll
  for (int k = 0; k < 9; k++) W[k] = ws[k];

  float a[2][2][3];
  #pragma unroll
  for (int c = 0; c < 3; c++) {
    a[0][0][c] = W[c];          a[0][1][c] = W[3+c] + W[6+c];
    a[1][0][c] = W[c] + W[3+c]; a[1][1][c] = W[6+c];
  }
  float* fo = f + (size_t)n*16;
  #pragma unroll
  for (int py = 0; py < 2; py++)
    #pragma unroll
    for (int px = 0; px < 2; px++) {
      int p = py*2 + px;
      #pragma unroll
      for (int ky = 0; ky < 2; ky++) {
        float kx0 = (px == 0) ? a[py][ky][0] : (a[py][ky][0] + a[py][ky][1]);
        float kx1 = (px == 0) ? (a[py][ky][1] + a[py][ky][2]) : a[py][ky][2];
        fo[p*4 + ky*2 + 0] = kx0;
        fo[p*4 + ky*2 + 1] = kx1;
      }
    }
}

// ---------------- scalar parity upconv: one thread per OUTPUT SCALAR ----------------
// blockIdx.y = co. Per-block LDS: that co's 4 parity weight sets, [p][ci] with
// stride Cin+1 float4s (parity blocks bank-offset 4 -> disjoint). Per thread:
// Cin x {4 pixel loads, 1 broadcast ds_read_b128, 4 FMA}. Max-parallelism shape
// for the small-spatial decoder layers (L3: 96, L4: 384, L5: 1536 blocks).
__global__ void k_upconv_s(const float* __restrict__ in, float* __restrict__ out,
                           const float* __restrict__ wfold, const float* __restrict__ bias,
                           int B, int Cin, int CO, int Hin)
{
  extern __shared__ float4 wlds4[];            // [4][Cin+1]
  int nt = blockDim.x, tid = threadIdx.x;
  int co = blockIdx.y;
  int stride = Cin + 1;
  const float4* wsrc = reinterpret_cast<const float4*>(wfold);
  for (int s = tid; s < Cin*4; s += nt) {
    int p = s & 3;
    int ci = s >> 2;
    wlds4[p*stride + ci] = wsrc[(size_t)(co*Cin + ci)*4 + p];
  }
  __syncthreads();

  int Hout = Hin * 2;
  int npix = B * Hout * Hout;
  int idx = blockIdx.x*nt + tid;
  if (idx >= npix) return;
  int x = idx % Hout;
  int y = (idx / Hout) % Hout;
  int b = idx / (Hout * Hout);

  int X = x >> 1, Y = y >> 1;
  int px = x & 1, py = y & 1;

  int r_lo = py ? Y : (Y > 0 ? Y-1 : 0);
  int r_hi = py ? (Y < Hin-1 ? Y+1 : Hin-1) : Y;
  int c_lo = px ? X : (X > 0 ? X-1 : 0);
  int c_hi = px ? (X < Hin-1 ? X+1 : Hin-1) : X;

  float acc = bias[co];

  const size_t plane = (size_t)Hin * Hin;
  const float* ibase = in + (size_t)b * Cin * plane;
  const float4* wb = wlds4 + (py*2 + px) * stride;

  for (int ci = 0; ci < Cin; ci++) {
    const float* ip = ibase + (size_t)ci * plane;
    const float* rl = ip + (size_t)r_lo * Hin;
    const float* rh = ip + (size_t)r_hi * Hin;
    float4 w4 = wb[ci];
    acc += w4.x*rl[c_lo] + w4.y*rl[c_hi] + w4.z*rh[c_lo] + w4.w*rh[c_hi];
  }

  float v = (acc >= 0.f) ? acc : 0.01f*acc;
  out[((size_t)b*CO + co)*((size_t)Hout*Hout) + (size_t)y*Hout + x] = v;
}

// ---------------- LDS-weight parity upconv: one thread per OUTPUT pixel ----------------
template<int CO>
__global__ void k_upconv_w(const float* __restrict__ in, float* __restrict__ out,
                           const float* __restrict__ wfold, const float* __restrict__ bias,
                           int B, int Cin, int Hin)
{
  extern __shared__ float4 wlds4[];           // [4][Cin*CO + 1]
  int nt = blockDim.x, tid = threadIdx.x;
  int stride = Cin * CO + 1;                  // +1 float4 pad: bank-offset 4 between parities
  int nw = Cin * CO * 4;
  const float4* wsrc = reinterpret_cast<const float4*>(wfold);
  for (int s = tid; s < nw; s += nt) {
    int p = s & 3;
    int r = s >> 2;            // co*Cin + ci
    int ci = r % Cin;
    int co = r / Cin;
    wlds4[p*stride + ci*CO + co] = wsrc[s];
  }
  __syncthreads();

  int Hout = Hin * 2;
  int total = B * Hout * Hout;
  int idx = blockIdx.x*nt + tid;
  if (idx >= total) return;
  int x = idx % Hout;
  int y = (idx / Hout) % Hout;
  int b = idx / (Hout * Hout);

  int X = x >> 1, Y = y >> 1;
  int px = x & 1, py = y & 1;

  int r_lo = py ? Y : (Y > 0 ? Y-1 : 0);
  int r_hi = py ? (Y < Hin-1 ? Y+1 : Hin-1) : Y;
  int c_lo = px ? X : (X > 0 ? X-1 : 0);
  int c_hi = px ? (X < Hin-1 ? X+1 : Hin-1) : X;

  float acc[CO];
  #pragma unroll
  for (int co = 0; co < CO; co++) acc[co] = bias[co];

  const size_t plane = (size_t)Hin * Hin;
  const float* ibase = in + (size_t)b * Cin * plane;
  const float4* wb = wlds4 + (py*2 + px) * stride;

  for (int ci = 0; ci < Cin; ci++) {
    const float* ip = ibase + (size_t)ci * plane;
    const float* rl = ip + (size_t)r_lo * Hin;
    const float* rh = ip + (size_t)r_hi * Hin;
    float p00 = rl[c_lo], p01 = rl[c_hi];
    float p10 = rh[c_lo], p11 = rh[c_hi];

    const float4* wc = wb + ci * CO;
    #pragma unroll
    for (int co = 0; co < CO; co++) {
      float4 w4 = wc[co];
      acc[co] += w4.x*p00 + w4.y*p01 + w4.z*p10 + w4.w*p11;
    }
  }

  int pix = y*Hout + x;
  #pragma unroll
  for (int co = 0; co < CO; co++) {
    float v = acc[co];
    v = (v >= 0.f) ? v : 0.01f*v;
    out[((size_t)b*CO + co)*((size_t)Hout*Hout) + pix] = v;
  }
}

// ---------------- paired LDS-weight upconv: one thread = outputs (x, x+Hout/2) ----------
template<int CO>
__global__ void k_upconv_w2(const float* __restrict__ in, float* __restrict__ out,
                            const float* __restrict__ wfold, const float* __restrict__ bias,
                            int B, int Cin, int Hin)
{
  extern __shared__ float4 wlds4[];           // [4][Cin*CO + 1]
  int nt = blockDim.x, tid = threadIdx.x;
  int stride = Cin * CO + 1;
  int nw = Cin * CO * 4;
  const float4* wsrc = reinterpret_cast<const float4*>(wfold);
  for (int s = tid; s < nw; s += nt) {
    int p = s & 3;
    int r = s >> 2;
    int ci = r % Cin;
    int co = r / Cin;
    wlds4[p*stride + ci*CO + co] = wsrc[s];
  }
  __syncthreads();

  int Hout = Hin * 2;
  int half = Hout >> 1;
  int total = B * Hout * half;
  int idx = blockIdx.x*nt + tid;
  if (idx >= total) return;
  int x1 = idx % half;
  int y  = (idx / half) % Hout;
  int b  = idx / (half * Hout);

  int px = x1 & 1, py = y & 1;
  int X1 = x1 >> 1, Y = y >> 1;
  int X2 = X1 + (Hin >> 1);

  int r_lo = py ? Y : (Y > 0 ? Y-1 : 0);
  int r_hi = py ? (Y < Hin-1 ? Y+1 : Hin-1) : Y;
  int c1lo = px ? X1 : (X1 > 0 ? X1-1 : 0);
  int c1hi = px ? (X1 < Hin-1 ? X1+1 : Hin-1) : X1;
  int c2lo = px ? X2 : (X2 > 0 ? X2-1 : 0);
  int c2hi = px ? (X2 < Hin-1 ? X2+1 : Hin-1) : X2;

  float acc0[CO], acc1[CO];
  #pragma unroll
  for (int co = 0; co < CO; co++) { float bv = bias[co]; acc0[co] = bv; acc1[co] = bv; }

  const size_t plane = (size_t)Hin * Hin;
  const float* ibase = in + (size_t)b * Cin * plane;
  const float4* wb = wlds4 + (py*2 + px) * stride;

  for (int ci = 0; ci < Cin; ci++) {
    const float* ip = ibase + (size_t)ci * plane;
    const float* rl = ip + (size_t)r_lo * Hin;
    const float* rh = ip + (size_t)r_hi * Hin;
    float a0 = rl[c1lo], a1 = rl[c1hi];
    float a2 = rh[c1lo], a3 = rh[c1hi];
    float b0 = rl[c2lo], b1 = rl[c2hi];
    float b2 = rh[c2lo], b3 = rh[c2hi];

    const float4* wc = wb + ci * CO;
    #pragma unroll
    for (int co = 0; co < CO; co++) {
      float4 w4 = wc[co];
      acc0[co] += w4.x*a0 + w4.y*a1 + w4.z*a2 + w4.w*a3;
      acc1[co] += w4.x*b0 + w4.y*b1 + w4.z*b2 + w4.w*b3;
    }
  }

  size_t oplane = (size_t)Hout * Hout;
  size_t pix1 = (size_t)y*Hout + x1;
  float* obase = out + (size_t)b * CO * oplane;
  #pragma unroll
  for (int co = 0; co < CO; co++) {
    float v0 = acc0[co]; v0 = (v0 >= 0.f) ? v0 : 0.01f*v0;
    float v1 = acc1[co]; v1 = (v1 >= 0.f) ? v1 : 0.01f*v1;
    float* op = obase + (size_t)co * oplane;
    op[pix1] = v0;
    op[pix1 + half] = v1;
  }
}

// ---------------- final: reflect-pad + 3x3 conv (16 -> 6) + tanh ----------------
__global__ void k_final(const float* __restrict__ in, float* __restrict__ out,
                        const float* __restrict__ w, const float* __restrict__ bias)
{
  int idx = blockIdx.x*blockDim.x + threadIdx.x;
  int total = 3 * HWP;
  if (idx >= total) return;
  int x = idx & (WWI-1);
  int y = (idx >> 9) & (HH-1);
  int b = idx / HWP;

  int ry[3], rx[3];
  #pragma unroll
  for (int d = 0; d < 3; d++) {
    int t = y - 1 + d;
    t = (t < 0) ? -t : t;
    ry[d] = (t >= HH) ? (2*(HH-1) - t) : t;
    t = x - 1 + d;
    t = (t < 0) ? -t : t;
    rx[d] = (t >= WWI) ? (2*(WWI-1) - t) : t;
  }

  float acc[6];
  #pragma unroll
  for (int co = 0; co < 6; co++) acc[co] = bias[co];

  for (int ci = 0; ci < 16; ci++) {
    const float* ib = in + ((size_t)(b*16) + ci) * HWP;
    float p[9];
    #pragma unroll
    for (int dy = 0; dy < 3; dy++)
      #pragma unroll
      for (int dx = 0; dx < 3; dx++)
        p[dy*3+dx] = ib[ry[dy]*WWI + rx[dx]];
    const float* wc = w + ci*9;
    #pragma unroll
    for (int co = 0; co < 6; co++) {
      const float* wcc = wc + co*16*9;
      #pragma unroll
      for (int k = 0; k < 9; k++) acc[co] += wcc[k] * p[k];
    }
  }

  int pix = y*WWI + x;
  #pragma unroll
  for (int co = 0; co < 6; co++)
    out[((size_t)(b*6) + co)*HWP + pix] = tanhf(acc[co]);
}

// ---------------- blending: fused grid-sample + weighting (all fp32) ----------------
__global__ void k_blend(const float* __restrict__ xin, const float* __restrict__ neighbors,
                        const int* __restrict__ aidx, const float* __restrict__ albedos,
                        const float* __restrict__ flows, float* __restrict__ out)
{
  int idx = blockIdx.x*blockDim.x + threadIdx.x;
  if (idx >= HWP) return;
  int xo = idx & (WWI-1);
  int yo = idx >> 9;

  float xv[9];
  #pragma unroll
  for (int i = 0; i < 9; i++) xv[i] = xin[i];

  float f0[6];
  #pragma unroll
  for (int c = 0; c < 6; c++) f0[c] = flows[(size_t)c*HWP + idx];

  const float* alb = albedos + (size_t)aidx[0]*3*HWP;
  float albp[3];
  #pragma unroll
  for (int ch = 0; ch < 3; ch++) albp[ch] = alb[(size_t)ch*HWP + idx];

  float num0 = 0.f, num1 = 0.f, num2 = 0.f;
  float wsum = 0.f;

  #pragma unroll
  for (int n = 0; n < 2; n++) {
    float dl = xv[0] - xv[(n+1)*3 + 0];
    float dv = xv[1] - xv[(n+1)*3 + 1];
    float dt = xv[2] - xv[(n+1)*3 + 2];
    bool fl = fabsf(dl) > 0.f;

    float ofx = dl*f0[0] + dv*f0[2] + dt*f0[4];
    float ofy = dl*f0[1] + dv*f0[3] + dt*f0[5];

    float gx = ((-1.f + (2.f/511.f)*(float)xo) + ofx + 1.f)*256.f - 0.5f;
    float gy = ((-1.f + (2.f/511.f)*(float)yo) + ofy + 1.f)*256.f - 0.5f;
    gx = fminf(fmaxf(gx, 0.f), 511.f);
    gy = fminf(fmaxf(gy, 0.f), 511.f);

    float x0f = floorf(gx), y0f = floorf(gy);
    float wx = gx - x0f, wy = gy - y0f;
    int x0i = (int)x0f, y0i = (int)y0f;
    int x1i = min(x0i + 1, WWI-1), y1i = min(y0i + 1, HH-1);

    float cw[4] = {(1.f-wx)*(1.f-wy), wx*(1.f-wy), (1.f-wx)*wy, wx*wy};
    int   cp[4] = {y0i*WWI + x0i, y0i*WWI + x1i, y1i*WWI + x0i, y1i*WWI + x1i};

    const float* nb = neighbors + (size_t)n*3*HWP;
    const float* Fn = flows + (size_t)(n+1)*6*HWP;

    float s0=0.f,s1=0.f,s2=0.f;
    float l0=0.f,l1=0.f,v0=0.f,v1=0.f,t0=0.f,t1=0.f;
    #pragma unroll
    for (int c = 0; c < 4; c++) {
      int p = cp[c];
      float ww = cw[c];
      float n0 = nb[p];
      float n1 = nb[HWP + p];
      float n2 = nb[2*HWP + p];
      if (fl) {
        n0 /= alb[p];
        n1 /= alb[HWP + p];
        n2 /= alb[2*HWP + p];
      }
      s0 += ww*n0; s1 += ww*n1; s2 += ww*n2;
      l0 += ww*Fn[p];             l1 += ww*Fn[HWP + p];
      v0 += ww*Fn[2*HWP + p];     v1 += ww*Fn[3*HWP + p];
      t0 += ww*Fn[4*HWP + p];     t1 += ww*Fn[5*HWP + p];
    }

    float wi0 = fl ? s0*albp[0] : s0;
    float wi1 = fl ? s1*albp[1] : s1;
    float wi2 = fl ? s2*albp[2] : s2;

    float obx = dl*l0 + dv*v0 + dt*t0;
    float oby = dl*l1 + dv*v1 + dt*t1;
    float dist = fabsf(ofx - obx) + fabsf(ofy - oby);
    float wgt = expf(-51.2f * dist);

    wsum += wgt;
    num0 += wgt*wi0; num1 += wgt*wi1; num2 += wgt*wi2;
  }

  float inv = 1.f / (wsum + 1e-5f);
  out[idx]         = num0*inv;
  out[HWP + idx]   = num1*inv;
  out[2*HWP + idx] = num2*inv;
}

// ---------------- launch ----------------
extern "C" void kernel_launch(void* const* d_in, const int* in_sizes, int n_in,
                              void* d_out, int out_size, void* d_ws, size_t ws_size,
                              hipStream_t stream) {
  const float* x         = (const float*)d_in[0];
  const float* neighbors = (const float*)d_in[1];
  const int*   aidx      = (const int*)d_in[2];
  const float* wts[10];
  const float* bis[10];
  for (int i = 0; i < 9; i++) { wts[i] = (const float*)d_in[3+2*i]; bis[i] = (const float*)d_in[4+2*i]; }
  wts[9] = (const float*)d_in[21];   // wf
  bis[9] = (const float*)d_in[22];   // bf
  const float* albedos = (const float*)d_in[23];

  float* wk   = (float*)d_ws;
  float* bufS = wk;                   // 792 floats (layer0 out)
  float* bufA = wk + 800;             // up to 4,718,592 floats
  float* bufB = bufA + 4718592;       // up to 12,582,912 floats
  size_t need = (size_t)(800 + 4718592 + 12582912) * 4;
  if (ws_size < need) return;

  // Folded-weight buffers in bufA slack [3,200,000, 3,281,920):
  // above L7's peak bufA use (3,145,728 floats); only overwritten by k_final
  // (4,718,592 floats) AFTER L8 consumed them. No workspace growth.
  float* wf3 = bufA + 3200000;            // 32*64*16 = 32768 floats
  float* wf4 = wf3 + 32768;               // 32*32*16 = 16384
  float* wf5 = wf4 + 16384;               // 32*32*16 = 16384
  float* wf6 = wf5 + 16384;               // 16*32*16 = 8192
  float* wf7 = wf6 + 8192;                // 16*16*16 = 4096
  float* wf8 = wf7 + 4096;                // 16*16*16 = 4096
  k_foldw6<<<20, 256, 0, stream>>>(wts[3], wts[4], wts[5], wts[6], wts[7], wts[8],
                                   wf3, wf4, wf5, wf6, wf7, wf8);

  k_layer0<<<1, 256, 0, stream>>>(x, wts[0], bis[0], bufS);

  auto spanOf = [](int Hin, int TR) { int s = TR/2 + 2; return (s > Hin) ? Hin : s; };
  auto ldsB = [&](int COB, int Cin, int Hin, int TR) {
    return (size_t)(COB*Cin*9 + COB + Cin*spanOf(Hin,TR)*Hin) * 4;
  };

  // L1: Cin=66 CO=64 Hin=2  | COB=4 TR=4 G=1 | blocks 3*1*16=48 (finer co-tiles)
  k_conv_lds<1><<<48, 256, ldsB(4,66,2,4), stream>>>(bufS, bufA, wts[1], bis[1],
                                                     3, 66, 64, 4, 2, 4, spanOf(2,4));
  // L2: Cin=64 CO=64 Hin=4  | COB=2 TR=8 G=1 | blocks 3*1*32=96 (finer co-tiles)
  k_conv_lds<1><<<96, 256, ldsB(2,64,4,8), stream>>>(bufA, bufB, wts[2], bis[2],
                                                     3, 64, 64, 2, 4, 8, spanOf(4,8));
  // L3-L5: scalar parity upconv, grid (npix/256, CO). LDS = 4*(Cin+1)*16 B.
  {
    dim3 g3(3*16*16/256, 32), g4(3*32*32/256, 32), g5(3*64*64/256, 32);
    k_upconv_s<<<g3, 256, (size_t)4*(64+1)*16, stream>>>(bufB, bufA, wf3, bis[3], 3, 64, 32, 8);
    k_upconv_s<<<g4, 256, (size_t)4*(32+1)*16, stream>>>(bufA, bufB, wf4, bis[4], 3, 32, 32, 16);
    k_upconv_s<<<g5, 256, (size_t)4*(32+1)*16, stream>>>(bufB, bufA, wf5, bis[5], 3, 32, 32, 32);
  }

  auto blocks = [](int total){ return (total + 255) / 256; };
  // L6: thread-per-output pixel, padded LDS weights.
  k_upconv_w<16><<<blocks(3*128*128), 256, (size_t)4*(32*16+1)*16, stream>>>(bufA, bufB, wf6, bis[6], 3, 32, 64);
  // L7/L8: paired outputs (x, x+Hout/2) -> 1 ds_read per 8 FMAs.
  k_upconv_w2<16><<<blocks(3*256*128), 256, (size_t)4*(16*16+1)*16, stream>>>(bufB, bufA, wf7, bis[7], 3, 16, 128);
  k_upconv_w2<16><<<blocks(3*512*256), 256, (size_t)4*(16*16+1)*16, stream>>>(bufA, bufB, wf8, bis[8], 3, 16, 256);

  k_final<<<blocks(3*HWP), 256, 0, stream>>>(bufB, bufA, wts[9], bis[9]);
  k_blend<<<blocks(HWP), 256, 0, stream>>>(x, neighbors, aidx, albedos, bufA, (float*)d_out);
}

// Round 10
// 321.163 us; speedup vs baseline: 1.7412x; 1.0345x over previous
//
#include <hip/hip_runtime.h>
#include <hip/hip_bf16.h>
#include <math.h>

// All inputs and the output are FLOAT32 (reference dtype). The "bf16" in the
// harness label is a literal string, not a dtype indicator.
//
// Upconv history:
//  R1/R3/R4: multi-output quad kernels spill (excess WRITE_SIZE tell).
//  R5: per-lane weight addresses -> vector L1 traffic -> slow.
//  R6: s_load-uniform weights -> latency-bound serial chains on tiny grids.
//  R7/R8: LDS parity weights (+1-float4 pad between parity blocks = disjoint
//    banks) + paired outputs. R9: 332us; L8 w2 top at 51us with SMALL SPILL
//    (VGPR=64, WRITE 58.4 vs 49.2MB ideal). k_final/L1/L2 are the rest.
//  Now: (1) L8 co-split (blockIdx.y, COB=8 -> acc[2][8]+8px ~45 live, no
//    spill); (2) k_final pairs adjacent x (12 loads / 2 outputs, s_load
//    weights); (3) L1/L2 parity-folded via k_upconv_s (fold extended w1..w8).

#define HH 512
#define WWI 512
#define HWP (HH*WWI)

// ---------------- layer 0: 1x1 conv on upsampled 2x2 + leakyrelu + coordconv ----------------
__global__ void k_layer0(const float* __restrict__ xin, const float* __restrict__ w,
                         const float* __restrict__ bias, float* __restrict__ out)
{
  for (int idx = threadIdx.x; idx < 3*66*4; idx += blockDim.x) {
    int pos = idx & 3;
    int c = (idx >> 2) % 66;
    int b = idx / (66*4);
    float v;
    if (c < 64) {
      float a = bias[c];
      #pragma unroll
      for (int ci = 0; ci < 3; ci++) a += w[c*3+ci] * xin[b*3+ci];
      v = (a >= 0.f) ? a : 0.01f*a;
    } else {
      int xx = pos & 1, yy = pos >> 1;
      v = (c == 64) ? 2.f*(float)xx : 2.f*(float)yy;
    }
    out[idx] = v;
  }
}

// ---------------- weight folding for upsample-conv parity decomposition ----------------
// upsample x2 + reflect-pad + 3x3 VALID conv == per-output-parity 2x2 conv on the
// ORIGINAL image (border reflect == clamp outer row/col; verified all Hin >= 2).
// Folded layout: f[((co*Cin + ci)*16) + p*4 + ky*2 + kx], p = py*2+px.
__global__ void k_foldw8(const float* __restrict__ w1, const float* __restrict__ w2,
                         const float* __restrict__ w3, const float* __restrict__ w4,
                         const float* __restrict__ w5, const float* __restrict__ w6,
                         const float* __restrict__ w7, const float* __restrict__ w8,
                         float* __restrict__ f1, float* __restrict__ f2,
                         float* __restrict__ f3, float* __restrict__ f4,
                         float* __restrict__ f5, float* __restrict__ f6,
                         float* __restrict__ f7, float* __restrict__ f8)
{
  int idx = blockIdx.x*blockDim.x + threadIdx.x;
  const float* w; float* f; int n;
  if      (idx < 4224)  { w = w1; f = f1; n = idx; }          // L1: 64x66
  else if (idx < 8320)  { w = w2; f = f2; n = idx - 4224; }   // L2: 64x64
  else if (idx < 10368) { w = w3; f = f3; n = idx - 8320; }   // L3: 32x64
  else if (idx < 11392) { w = w4; f = f4; n = idx - 10368; }  // L4: 32x32
  else if (idx < 12416) { w = w5; f = f5; n = idx - 11392; }  // L5: 32x32
  else if (idx < 12928) { w = w6; f = f6; n = idx - 12416; }  // L6: 16x32
  else if (idx < 13184) { w = w7; f = f7; n = idx - 12928; }  // L7: 16x16
  else if (idx < 13440) { w = w8; f = f8; n = idx - 13184; }  // L8: 16x16
  else return;

  const float* ws = w + (size_t)n*9;
  float W[9];
  #pragma unroll
  for (int k = 0; k < 9; k++) W[k] = ws[k];

  float a[2][2][3];
  #pragma unroll
  for (int c = 0; c < 3; c++) {
    a[0][0][c] = W[c];          a[0][1][c] = W[3+c] + W[6+c];
    a[1][0][c] = W[c] + W[3+c]; a[1][1][c] = W[6+c];
  }
  float* fo = f + (size_t)n*16;
  #pragma unroll
  for (int py = 0; py < 2; py++)
    #pragma unroll
    for (int px = 0; px < 2; px++) {
      int p = py*2 + px;
      #pragma unroll
      for (int ky = 0; ky < 2; ky++) {
        float kx0 = (px == 0) ? a[py][ky][0] : (a[py][ky][0] + a[py][ky][1]);
        float kx1 = (px == 0) ? (a[py][ky][1] + a[py][ky][2]) : a[py][ky][2];
        fo[p*4 + ky*2 + 0] = kx0;
        fo[p*4 + ky*2 + 1] = kx1;
      }
    }
}

// ---------------- scalar parity upconv: one thread per OUTPUT SCALAR ----------------
// blockIdx.y = co. LDS: that co's 4 parity weight sets, [p][ci], stride Cin+1
// float4s (parity blocks bank-offset 4 -> disjoint).
__global__ void k_upconv_s(const float* __restrict__ in, float* __restrict__ out,
                           const float* __restrict__ wfold, const float* __restrict__ bias,
                           int B, int Cin, int CO, int Hin)
{
  extern __shared__ float4 wlds4[];            // [4][Cin+1]
  int nt = blockDim.x, tid = threadIdx.x;
  int co = blockIdx.y;
  int stride = Cin + 1;
  const float4* wsrc = reinterpret_cast<const float4*>(wfold);
  for (int s = tid; s < Cin*4; s += nt) {
    int p = s & 3;
    int ci = s >> 2;
    wlds4[p*stride + ci] = wsrc[(size_t)(co*Cin + ci)*4 + p];
  }
  __syncthreads();

  int Hout = Hin * 2;
  int npix = B * Hout * Hout;
  int idx = blockIdx.x*nt + tid;
  if (idx >= npix) return;
  int x = idx % Hout;
  int y = (idx / Hout) % Hout;
  int b = idx / (Hout * Hout);

  int X = x >> 1, Y = y >> 1;
  int px = x & 1, py = y & 1;

  int r_lo = py ? Y : (Y > 0 ? Y-1 : 0);
  int r_hi = py ? (Y < Hin-1 ? Y+1 : Hin-1) : Y;
  int c_lo = px ? X : (X > 0 ? X-1 : 0);
  int c_hi = px ? (X < Hin-1 ? X+1 : Hin-1) : X;

  float acc = bias[co];

  const size_t plane = (size_t)Hin * Hin;
  const float* ibase = in + (size_t)b * Cin * plane;
  const float4* wb = wlds4 + (py*2 + px) * stride;

  for (int ci = 0; ci < Cin; ci++) {
    const float* ip = ibase + (size_t)ci * plane;
    const float* rl = ip + (size_t)r_lo * Hin;
    const float* rh = ip + (size_t)r_hi * Hin;
    float4 w4 = wb[ci];
    acc += w4.x*rl[c_lo] + w4.y*rl[c_hi] + w4.z*rh[c_lo] + w4.w*rh[c_hi];
  }

  float v = (acc >= 0.f) ? acc : 0.01f*acc;
  out[((size_t)b*CO + co)*((size_t)Hout*Hout) + (size_t)y*Hout + x] = v;
}

// ---------------- LDS-weight parity upconv: one thread per OUTPUT pixel ----------------
template<int CO>
__global__ void k_upconv_w(const float* __restrict__ in, float* __restrict__ out,
                           const float* __restrict__ wfold, const float* __restrict__ bias,
                           int B, int Cin, int Hin)
{
  extern __shared__ float4 wlds4[];           // [4][Cin*CO + 1]
  int nt = blockDim.x, tid = threadIdx.x;
  int stride = Cin * CO + 1;                  // +1 float4 pad between parity blocks
  int nw = Cin * CO * 4;
  const float4* wsrc = reinterpret_cast<const float4*>(wfold);
  for (int s = tid; s < nw; s += nt) {
    int p = s & 3;
    int r = s >> 2;            // co*Cin + ci
    int ci = r % Cin;
    int co = r / Cin;
    wlds4[p*stride + ci*CO + co] = wsrc[s];
  }
  __syncthreads();

  int Hout = Hin * 2;
  int total = B * Hout * Hout;
  int idx = blockIdx.x*nt + tid;
  if (idx >= total) return;
  int x = idx % Hout;
  int y = (idx / Hout) % Hout;
  int b = idx / (Hout * Hout);

  int X = x >> 1, Y = y >> 1;
  int px = x & 1, py = y & 1;

  int r_lo = py ? Y : (Y > 0 ? Y-1 : 0);
  int r_hi = py ? (Y < Hin-1 ? Y+1 : Hin-1) : Y;
  int c_lo = px ? X : (X > 0 ? X-1 : 0);
  int c_hi = px ? (X < Hin-1 ? X+1 : Hin-1) : X;

  float acc[CO];
  #pragma unroll
  for (int co = 0; co < CO; co++) acc[co] = bias[co];

  const size_t plane = (size_t)Hin * Hin;
  const float* ibase = in + (size_t)b * Cin * plane;
  const float4* wb = wlds4 + (py*2 + px) * stride;

  for (int ci = 0; ci < Cin; ci++) {
    const float* ip = ibase + (size_t)ci * plane;
    const float* rl = ip + (size_t)r_lo * Hin;
    const float* rh = ip + (size_t)r_hi * Hin;
    float p00 = rl[c_lo], p01 = rl[c_hi];
    float p10 = rh[c_lo], p11 = rh[c_hi];

    const float4* wc = wb + ci * CO;
    #pragma unroll
    for (int co = 0; co < CO; co++) {
      float4 w4 = wc[co];
      acc[co] += w4.x*p00 + w4.y*p01 + w4.z*p10 + w4.w*p11;
    }
  }

  int pix = y*Hout + x;
  #pragma unroll
  for (int co = 0; co < CO; co++) {
    float v = acc[co];
    v = (v >= 0.f) ? v : 0.01f*v;
    out[((size_t)b*CO + co)*((size_t)Hout*Hout) + pix] = v;
  }
}

// ---------------- paired + co-split LDS-weight upconv ----------------
// One thread = outputs (x1, x1+Hout/2) for COB channels; blockIdx.y = co-slice.
// COB=8: acc[2][8]=16 regs + 8 pixels ~45 live -> no spill in the 64 bucket.
template<int COB>
__global__ void k_upconv_w2c(const float* __restrict__ in, float* __restrict__ out,
                             const float* __restrict__ wfold, const float* __restrict__ bias,
                             int B, int Cin, int CO, int Hin)
{
  extern __shared__ float4 wlds4[];           // [4][Cin*COB + 1]
  int nt = blockDim.x, tid = threadIdx.x;
  int co0 = blockIdx.y * COB;
  int stride = Cin * COB + 1;
  int nw = Cin * COB * 4;
  const float4* wsrc = reinterpret_cast<const float4*>(wfold);
  for (int s = tid; s < nw; s += nt) {
    int p = s & 3;
    int r = s >> 2;            // col*Cin + ci  (col = local co)
    int ci = r % Cin;
    int col = r / Cin;
    wlds4[p*stride + ci*COB + col] = wsrc[(size_t)((co0 + col)*Cin + ci)*4 + p];
  }
  __syncthreads();

  int Hout = Hin * 2;
  int half = Hout >> 1;
  int total = B * Hout * half;
  int idx = blockIdx.x*nt + tid;
  if (idx >= total) return;
  int x1 = idx % half;
  int y  = (idx / half) % Hout;
  int b  = idx / (half * Hout);

  int px = x1 & 1, py = y & 1;
  int X1 = x1 >> 1, Y = y >> 1;
  int X2 = X1 + (Hin >> 1);

  int r_lo = py ? Y : (Y > 0 ? Y-1 : 0);
  int r_hi = py ? (Y < Hin-1 ? Y+1 : Hin-1) : Y;
  int c1lo = px ? X1 : (X1 > 0 ? X1-1 : 0);
  int c1hi = px ? (X1 < Hin-1 ? X1+1 : Hin-1) : X1;
  int c2lo = px ? X2 : (X2 > 0 ? X2-1 : 0);
  int c2hi = px ? (X2 < Hin-1 ? X2+1 : Hin-1) : X2;

  float acc0[COB], acc1[COB];
  #pragma unroll
  for (int j = 0; j < COB; j++) { float bv = bias[co0 + j]; acc0[j] = bv; acc1[j] = bv; }

  const size_t plane = (size_t)Hin * Hin;
  const float* ibase = in + (size_t)b * Cin * plane;
  const float4* wb = wlds4 + (py*2 + px) * stride;

  for (int ci = 0; ci < Cin; ci++) {
    const float* ip = ibase + (size_t)ci * plane;
    const float* rl = ip + (size_t)r_lo * Hin;
    const float* rh = ip + (size_t)r_hi * Hin;
    float a0 = rl[c1lo], a1 = rl[c1hi];
    float a2 = rh[c1lo], a3 = rh[c1hi];
    float b0 = rl[c2lo], b1 = rl[c2hi];
    float b2 = rh[c2lo], b3 = rh[c2hi];

    const float4* wc = wb + ci * COB;
    #pragma unroll
    for (int j = 0; j < COB; j++) {
      float4 w4 = wc[j];
      acc0[j] += w4.x*a0 + w4.y*a1 + w4.z*a2 + w4.w*a3;
      acc1[j] += w4.x*b0 + w4.y*b1 + w4.z*b2 + w4.w*b3;
    }
  }

  size_t oplane = (size_t)Hout * Hout;
  size_t pix1 = (size_t)y*Hout + x1;
  float* op = out + ((size_t)b * CO + co0) * oplane;
  #pragma unroll
  for (int j = 0; j < COB; j++) {
    float v0 = acc0[j]; v0 = (v0 >= 0.f) ? v0 : 0.01f*v0;
    float v1 = acc1[j]; v1 = (v1 >= 0.f) ? v1 : 0.01f*v1;
    op[pix1] = v0;
    op[pix1 + half] = v1;
    op += oplane;              // incremental: no per-co 64-bit mul
  }
}

// ---------------- final: reflect-pad + 3x3 conv (16 -> 6) + tanh, paired x ----------------
// One thread = outputs (x0, x0+1): 12 pixel loads serve both (6/output vs 9).
// Weight addresses are loop-uniform -> s_load path. float2 coalesced stores.
__global__ void k_final2(const float* __restrict__ in, float* __restrict__ out,
                         const float* __restrict__ w, const float* __restrict__ bias)
{
  int idx = blockIdx.x*blockDim.x + threadIdx.x;
  int total = 3 * HH * (WWI/2);
  if (idx >= total) return;
  int xh = idx % (WWI/2);
  int y  = (idx / (WWI/2)) % HH;
  int b  = idx / (HH * (WWI/2));
  int x0 = 2*xh;

  int ry[3];
  #pragma unroll
  for (int d = 0; d < 3; d++) {
    int t = y - 1 + d;
    t = (t < 0) ? -t : t;
    ry[d] = (t >= HH) ? (2*(HH-1) - t) : t;
  }
  // columns x0-1, x0, x0+1, x0+2 with reflect (x0 even, 0..510)
  int cx[4];
  cx[0] = (x0 == 0) ? 1 : x0-1;
  cx[1] = x0;
  cx[2] = x0+1;
  cx[3] = (x0+2 >= WWI) ? (2*(WWI-1) - (x0+2)) : x0+2;

  float acc0[6], acc1[6];
  #pragma unroll
  for (int co = 0; co < 6; co++) { float bv = bias[co]; acc0[co] = bv; acc1[co] = bv; }

  for (int ci = 0; ci < 16; ci++) {
    const float* ib = in + ((size_t)(b*16) + ci) * HWP;
    float p[3][4];
    #pragma unroll
    for (int dy = 0; dy < 3; dy++) {
      const float* r = ib + (size_t)ry[dy]*WWI;
      #pragma unroll
      for (int dx = 0; dx < 4; dx++) p[dy][dx] = r[cx[dx]];
    }
    const float* wc = w + ci*9;
    #pragma unroll
    for (int co = 0; co < 6; co++) {
      const float* wcc = wc + co*16*9;
      #pragma unroll
      for (int dy = 0; dy < 3; dy++) {
        #pragma unroll
        for (int dx = 0; dx < 3; dx++) {
          float wv = wcc[dy*3+dx];
          acc0[co] += wv * p[dy][dx];
          acc1[co] += wv * p[dy][dx+1];
        }
      }
    }
  }

  size_t pix = (size_t)y*WWI + x0;
  #pragma unroll
  for (int co = 0; co < 6; co++) {
    float2 v = make_float2(tanhf(acc0[co]), tanhf(acc1[co]));
    *reinterpret_cast<float2*>(out + ((size_t)(b*6) + co)*HWP + pix) = v;
  }
}

// ---------------- blending: fused grid-sample + weighting (all fp32) ----------------
__global__ void k_blend(const float* __restrict__ xin, const float* __restrict__ neighbors,
                        const int* __restrict__ aidx, const float* __restrict__ albedos,
                        const float* __restrict__ flows, float* __restrict__ out)
{
  int idx = blockIdx.x*blockDim.x + threadIdx.x;
  if (idx >= HWP) return;
  int xo = idx & (WWI-1);
  int yo = idx >> 9;

  float xv[9];
  #pragma unroll
  for (int i = 0; i < 9; i++) xv[i] = xin[i];

  float f0[6];
  #pragma unroll
  for (int c = 0; c < 6; c++) f0[c] = flows[(size_t)c*HWP + idx];

  const float* alb = albedos + (size_t)aidx[0]*3*HWP;
  float albp[3];
  #pragma unroll
  for (int ch = 0; ch < 3; ch++) albp[ch] = alb[(size_t)ch*HWP + idx];

  float num0 = 0.f, num1 = 0.f, num2 = 0.f;
  float wsum = 0.f;

  #pragma unroll
  for (int n = 0; n < 2; n++) {
    float dl = xv[0] - xv[(n+1)*3 + 0];
    float dv = xv[1] - xv[(n+1)*3 + 1];
    float dt = xv[2] - xv[(n+1)*3 + 2];
    bool fl = fabsf(dl) > 0.f;

    float ofx = dl*f0[0] + dv*f0[2] + dt*f0[4];
    float ofy = dl*f0[1] + dv*f0[3] + dt*f0[5];

    float gx = ((-1.f + (2.f/511.f)*(float)xo) + ofx + 1.f)*256.f - 0.5f;
    float gy = ((-1.f + (2.f/511.f)*(float)yo) + ofy + 1.f)*256.f - 0.5f;
    gx = fminf(fmaxf(gx, 0.f), 511.f);
    gy = fminf(fmaxf(gy, 0.f), 511.f);

    float x0f = floorf(gx), y0f = floorf(gy);
    float wx = gx - x0f, wy = gy - y0f;
    int x0i = (int)x0f, y0i = (int)y0f;
    int x1i = min(x0i + 1, WWI-1), y1i = min(y0i + 1, HH-1);

    float cw[4] = {(1.f-wx)*(1.f-wy), wx*(1.f-wy), (1.f-wx)*wy, wx*wy};
    int   cp[4] = {y0i*WWI + x0i, y0i*WWI + x1i, y1i*WWI + x0i, y1i*WWI + x1i};

    const float* nb = neighbors + (size_t)n*3*HWP;
    const float* Fn = flows + (size_t)(n+1)*6*HWP;

    float s0=0.f,s1=0.f,s2=0.f;
    float l0=0.f,l1=0.f,v0=0.f,v1=0.f,t0=0.f,t1=0.f;
    #pragma unroll
    for (int c = 0; c < 4; c++) {
      int p = cp[c];
      float ww = cw[c];
      float n0 = nb[p];
      float n1 = nb[HWP + p];
      float n2 = nb[2*HWP + p];
      if (fl) {
        n0 /= alb[p];
        n1 /= alb[HWP + p];
        n2 /= alb[2*HWP + p];
      }
      s0 += ww*n0; s1 += ww*n1; s2 += ww*n2;
      l0 += ww*Fn[p];             l1 += ww*Fn[HWP + p];
      v0 += ww*Fn[2*HWP + p];     v1 += ww*Fn[3*HWP + p];
      t0 += ww*Fn[4*HWP + p];     t1 += ww*Fn[5*HWP + p];
    }

    float wi0 = fl ? s0*albp[0] : s0;
    float wi1 = fl ? s1*albp[1] : s1;
    float wi2 = fl ? s2*albp[2] : s2;

    float obx = dl*l0 + dv*v0 + dt*t0;
    float oby = dl*l1 + dv*v1 + dt*t1;
    float dist = fabsf(ofx - obx) + fabsf(ofy - oby);
    float wgt = expf(-51.2f * dist);

    wsum += wgt;
    num0 += wgt*wi0; num1 += wgt*wi1; num2 += wgt*wi2;
  }

  float inv = 1.f / (wsum + 1e-5f);
  out[idx]         = num0*inv;
  out[HWP + idx]   = num1*inv;
  out[2*HWP + idx] = num2*inv;
}

// ---------------- launch ----------------
extern "C" void kernel_launch(void* const* d_in, const int* in_sizes, int n_in,
                              void* d_out, int out_size, void* d_ws, size_t ws_size,
                              hipStream_t stream) {
  const float* x         = (const float*)d_in[0];
  const float* neighbors = (const float*)d_in[1];
  const int*   aidx      = (const int*)d_in[2];
  const float* wts[10];
  const float* bis[10];
  for (int i = 0; i < 9; i++) { wts[i] = (const float*)d_in[3+2*i]; bis[i] = (const float*)d_in[4+2*i]; }
  wts[9] = (const float*)d_in[21];   // wf
  bis[9] = (const float*)d_in[22];   // bf
  const float* albedos = (const float*)d_in[23];

  float* wk   = (float*)d_ws;
  float* bufS = wk;                   // 792 floats (layer0 out)
  float* bufA = wk + 800;             // up to 4,718,592 floats
  float* bufB = bufA + 4718592;       // up to 12,582,912 floats
  size_t need = (size_t)(800 + 4718592 + 12582912) * 4;
  if (ws_size < need) return;

  // Folded weights in bufA slack [3,200,000, 3,415,040): above L7's peak bufA
  // use (3,145,728 floats); overwritten only by k_final (4,718,592) AFTER L8
  // consumed them; k_blend reads flows (1.57M) below. No workspace growth.
  float* wf1 = bufA + 3200000;            // 64*66*16 = 67584
  float* wf2 = wf1 + 67584;               // 64*64*16 = 65536
  float* wf3 = wf2 + 65536;               // 32*64*16 = 32768
  float* wf4 = wf3 + 32768;               // 32*32*16 = 16384
  float* wf5 = wf4 + 16384;               // 32*32*16 = 16384
  float* wf6 = wf5 + 16384;               // 16*32*16 = 8192
  float* wf7 = wf6 + 8192;                // 16*16*16 = 4096
  float* wf8 = wf7 + 4096;                // 16*16*16 = 4096
  k_foldw8<<<53, 256, 0, stream>>>(wts[1], wts[2], wts[3], wts[4], wts[5], wts[6], wts[7], wts[8],
                                   wf1, wf2, wf3, wf4, wf5, wf6, wf7, wf8);

  k_layer0<<<1, 256, 0, stream>>>(x, wts[0], bis[0], bufS);

  auto blocks = [](int total){ return (total + 255) / 256; };

  // L1-L5: scalar parity upconv, grid (npix/256, CO). LDS = 4*(Cin+1)*16 B.
  {
    dim3 g1(blocks(3*4*4), 64), g2(blocks(3*8*8), 64);
    dim3 g3(blocks(3*16*16), 32), g4(blocks(3*32*32), 32), g5(blocks(3*64*64), 32);
    k_upconv_s<<<g1, 256, (size_t)4*(66+1)*16, stream>>>(bufS, bufA, wf1, bis[1], 3, 66, 64, 2);
    k_upconv_s<<<g2, 256, (size_t)4*(64+1)*16, stream>>>(bufA, bufB, wf2, bis[2], 3, 64, 64, 4);
    k_upconv_s<<<g3, 256, (size_t)4*(64+1)*16, stream>>>(bufB, bufA, wf3, bis[3], 3, 64, 32, 8);
    k_upconv_s<<<g4, 256, (size_t)4*(32+1)*16, stream>>>(bufA, bufB, wf4, bis[4], 3, 32, 32, 16);
    k_upconv_s<<<g5, 256, (size_t)4*(32+1)*16, stream>>>(bufB, bufA, wf5, bis[5], 3, 32, 32, 32);
  }

  // L6: thread-per-output pixel, padded LDS weights.
  k_upconv_w<16><<<blocks(3*128*128), 256, (size_t)4*(32*16+1)*16, stream>>>(bufA, bufB, wf6, bis[6], 3, 32, 64);
  // L7: paired outputs, full CO (proven ~13us shape).
  {
    dim3 g7(blocks(3*256*128), 1);
    k_upconv_w2c<16><<<g7, 256, (size_t)4*(16*16+1)*16, stream>>>(bufB, bufA, wf7, bis[7], 3, 16, 16, 128);
  }
  // L8: paired + co-split x2 (COB=8 -> no spill).
  {
    dim3 g8(blocks(3*512*256), 2);
    k_upconv_w2c<8><<<g8, 256, (size_t)4*(16*8+1)*16, stream>>>(bufA, bufB, wf8, bis[8], 3, 16, 16, 256);
  }

  // final: paired-x conv + tanh.
  k_final2<<<blocks(3*HH*(WWI/2)), 256, 0, stream>>>(bufB, bufA, wts[9], bis[9]);
  k_blend<<<blocks(HWP), 256, 0, stream>>>(x, neighbors, aidx, albedos, bufA, (float*)d_out);
}

// Round 11
// 308.445 us; speedup vs baseline: 1.8130x; 1.0412x over previous
//
#include <hip/hip_runtime.h>
#include <hip/hip_bf16.h>
#include <math.h>

// All inputs and the output are FLOAT32 (reference dtype). The "bf16" in the
// harness label is a literal string, not a dtype indicator.
//
// Upconv history:
//  R1/R3/R4: multi-output quad kernels spill (excess WRITE_SIZE tell).
//  R5: per-lane weight addresses -> vector L1 traffic -> slow.
//  R6: s_load-uniform weights -> latency-bound serial chains on tiny grids.
//  R7/R8: LDS parity weights (+1-float4 pad = disjoint banks) + paired outputs.
//  R9: co-split COB=8 fixed L8 spill (VGPR 44, WRITE ideal) -> 321us.
//  R10 profile: L8 = 47us, FETCH 49.2MB = 4x input. Each input row feeds 4
//    output rows; adjacent-y blocks land on different XCDs (round-robin) ->
//    no cross-block L2 reuse. Also L7 was still the spilling <16> shape.
//  Now: XCD-aware blockIdx.x swizzle (contiguous y-chunks per XCD) on
//    k_upconv_w/w2c/final2; L7 -> w2c<8> (proven 44-VGPR shape).

#define HH 512
#define WWI 512
#define HWP (HH*WWI)

// Contiguous-chunk XCD swizzle (bijective when nwg % 8 == 0).
__device__ __forceinline__ int xcd_swz(int bx, int nbx) {
  if ((nbx & 7) == 0) {
    int c = nbx >> 3;
    return (bx & 7) * c + (bx >> 3);
  }
  return bx;
}

// ---------------- layer 0: 1x1 conv on upsampled 2x2 + leakyrelu + coordconv ----------------
__global__ void k_layer0(const float* __restrict__ xin, const float* __restrict__ w,
                         const float* __restrict__ bias, float* __restrict__ out)
{
  for (int idx = threadIdx.x; idx < 3*66*4; idx += blockDim.x) {
    int pos = idx & 3;
    int c = (idx >> 2) % 66;
    int b = idx / (66*4);
    float v;
    if (c < 64) {
      float a = bias[c];
      #pragma unroll
      for (int ci = 0; ci < 3; ci++) a += w[c*3+ci] * xin[b*3+ci];
      v = (a >= 0.f) ? a : 0.01f*a;
    } else {
      int xx = pos & 1, yy = pos >> 1;
      v = (c == 64) ? 2.f*(float)xx : 2.f*(float)yy;
    }
    out[idx] = v;
  }
}

// ---------------- weight folding for upsample-conv parity decomposition ----------------
// upsample x2 + reflect-pad + 3x3 VALID conv == per-output-parity 2x2 conv on the
// ORIGINAL image (border reflect == clamp outer row/col; verified all Hin >= 2).
// Folded layout: f[((co*Cin + ci)*16) + p*4 + ky*2 + kx], p = py*2+px.
__global__ void k_foldw8(const float* __restrict__ w1, const float* __restrict__ w2,
                         const float* __restrict__ w3, const float* __restrict__ w4,
                         const float* __restrict__ w5, const float* __restrict__ w6,
                         const float* __restrict__ w7, const float* __restrict__ w8,
                         float* __restrict__ f1, float* __restrict__ f2,
                         float* __restrict__ f3, float* __restrict__ f4,
                         float* __restrict__ f5, float* __restrict__ f6,
                         float* __restrict__ f7, float* __restrict__ f8)
{
  int idx = blockIdx.x*blockDim.x + threadIdx.x;
  const float* w; float* f; int n;
  if      (idx < 4224)  { w = w1; f = f1; n = idx; }          // L1: 64x66
  else if (idx < 8320)  { w = w2; f = f2; n = idx - 4224; }   // L2: 64x64
  else if (idx < 10368) { w = w3; f = f3; n = idx - 8320; }   // L3: 32x64
  else if (idx < 11392) { w = w4; f = f4; n = idx - 10368; }  // L4: 32x32
  else if (idx < 12416) { w = w5; f = f5; n = idx - 11392; }  // L5: 32x32
  else if (idx < 12928) { w = w6; f = f6; n = idx - 12416; }  // L6: 16x32
  else if (idx < 13184) { w = w7; f = f7; n = idx - 12928; }  // L7: 16x16
  else if (idx < 13440) { w = w8; f = f8; n = idx - 13184; }  // L8: 16x16
  else return;

  const float* ws = w + (size_t)n*9;
  float W[9];
  #pragma unroll
  for (int k = 0; k < 9; k++) W[k] = ws[k];

  float a[2][2][3];
  #pragma unroll
  for (int c = 0; c < 3; c++) {
    a[0][0][c] = W[c];          a[0][1][c] = W[3+c] + W[6+c];
    a[1][0][c] = W[c] + W[3+c]; a[1][1][c] = W[6+c];
  }
  float* fo = f + (size_t)n*16;
  #pragma unroll
  for (int py = 0; py < 2; py++)
    #pragma unroll
    for (int px = 0; px < 2; px++) {
      int p = py*2 + px;
      #pragma unroll
      for (int ky = 0; ky < 2; ky++) {
        float kx0 = (px == 0) ? a[py][ky][0] : (a[py][ky][0] + a[py][ky][1]);
        float kx1 = (px == 0) ? (a[py][ky][1] + a[py][ky][2]) : a[py][ky][2];
        fo[p*4 + ky*2 + 0] = kx0;
        fo[p*4 + ky*2 + 1] = kx1;
      }
    }
}

// ---------------- scalar parity upconv: one thread per OUTPUT SCALAR ----------------
// blockIdx.y = co. LDS: that co's 4 parity weight sets, [p][ci], stride Cin+1
// float4s (parity blocks bank-offset 4 -> disjoint).
__global__ void k_upconv_s(const float* __restrict__ in, float* __restrict__ out,
                           const float* __restrict__ wfold, const float* __restrict__ bias,
                           int B, int Cin, int CO, int Hin)
{
  extern __shared__ float4 wlds4[];            // [4][Cin+1]
  int nt = blockDim.x, tid = threadIdx.x;
  int co = blockIdx.y;
  int stride = Cin + 1;
  const float4* wsrc = reinterpret_cast<const float4*>(wfold);
  for (int s = tid; s < Cin*4; s += nt) {
    int p = s & 3;
    int ci = s >> 2;
    wlds4[p*stride + ci] = wsrc[(size_t)(co*Cin + ci)*4 + p];
  }
  __syncthreads();

  int Hout = Hin * 2;
  int npix = B * Hout * Hout;
  int idx = blockIdx.x*nt + tid;
  if (idx >= npix) return;
  int x = idx % Hout;
  int y = (idx / Hout) % Hout;
  int b = idx / (Hout * Hout);

  int X = x >> 1, Y = y >> 1;
  int px = x & 1, py = y & 1;

  int r_lo = py ? Y : (Y > 0 ? Y-1 : 0);
  int r_hi = py ? (Y < Hin-1 ? Y+1 : Hin-1) : Y;
  int c_lo = px ? X : (X > 0 ? X-1 : 0);
  int c_hi = px ? (X < Hin-1 ? X+1 : Hin-1) : X;

  float acc = bias[co];

  const size_t plane = (size_t)Hin * Hin;
  const float* ibase = in + (size_t)b * Cin * plane;
  const float4* wb = wlds4 + (py*2 + px) * stride;

  for (int ci = 0; ci < Cin; ci++) {
    const float* ip = ibase + (size_t)ci * plane;
    const float* rl = ip + (size_t)r_lo * Hin;
    const float* rh = ip + (size_t)r_hi * Hin;
    float4 w4 = wb[ci];
    acc += w4.x*rl[c_lo] + w4.y*rl[c_hi] + w4.z*rh[c_lo] + w4.w*rh[c_hi];
  }

  float v = (acc >= 0.f) ? acc : 0.01f*acc;
  out[((size_t)b*CO + co)*((size_t)Hout*Hout) + (size_t)y*Hout + x] = v;
}

// ---------------- LDS-weight parity upconv: one thread per OUTPUT pixel ----------------
template<int CO>
__global__ void k_upconv_w(const float* __restrict__ in, float* __restrict__ out,
                           const float* __restrict__ wfold, const float* __restrict__ bias,
                           int B, int Cin, int Hin)
{
  extern __shared__ float4 wlds4[];           // [4][Cin*CO + 1]
  int nt = blockDim.x, tid = threadIdx.x;
  int stride = Cin * CO + 1;                  // +1 float4 pad between parity blocks
  int nw = Cin * CO * 4;
  const float4* wsrc = reinterpret_cast<const float4*>(wfold);
  for (int s = tid; s < nw; s += nt) {
    int p = s & 3;
    int r = s >> 2;            // co*Cin + ci
    int ci = r % Cin;
    int co = r / Cin;
    wlds4[p*stride + ci*CO + co] = wsrc[s];
  }
  __syncthreads();

  int Hout = Hin * 2;
  int total = B * Hout * Hout;
  int bx = xcd_swz(blockIdx.x, gridDim.x);
  int idx = bx*nt + tid;
  if (idx >= total) return;
  int x = idx % Hout;
  int y = (idx / Hout) % Hout;
  int b = idx / (Hout * Hout);

  int X = x >> 1, Y = y >> 1;
  int px = x & 1, py = y & 1;

  int r_lo = py ? Y : (Y > 0 ? Y-1 : 0);
  int r_hi = py ? (Y < Hin-1 ? Y+1 : Hin-1) : Y;
  int c_lo = px ? X : (X > 0 ? X-1 : 0);
  int c_hi = px ? (X < Hin-1 ? X+1 : Hin-1) : X;

  float acc[CO];
  #pragma unroll
  for (int co = 0; co < CO; co++) acc[co] = bias[co];

  const size_t plane = (size_t)Hin * Hin;
  const float* ibase = in + (size_t)b * Cin * plane;
  const float4* wb = wlds4 + (py*2 + px) * stride;

  for (int ci = 0; ci < Cin; ci++) {
    const float* ip = ibase + (size_t)ci * plane;
    const float* rl = ip + (size_t)r_lo * Hin;
    const float* rh = ip + (size_t)r_hi * Hin;
    float p00 = rl[c_lo], p01 = rl[c_hi];
    float p10 = rh[c_lo], p11 = rh[c_hi];

    const float4* wc = wb + ci * CO;
    #pragma unroll
    for (int co = 0; co < CO; co++) {
      float4 w4 = wc[co];
      acc[co] += w4.x*p00 + w4.y*p01 + w4.z*p10 + w4.w*p11;
    }
  }

  int pix = y*Hout + x;
  #pragma unroll
  for (int co = 0; co < CO; co++) {
    float v = acc[co];
    v = (v >= 0.f) ? v : 0.01f*v;
    out[((size_t)b*CO + co)*((size_t)Hout*Hout) + pix] = v;
  }
}

// ---------------- paired + co-split LDS-weight upconv ----------------
// One thread = outputs (x1, x1+Hout/2) for COB channels; blockIdx.y = co-slice.
// COB=8: acc[2][8]=16 regs + 8 pixels ~45 live -> VGPR 44 measured, no spill.
template<int COB>
__global__ void k_upconv_w2c(const float* __restrict__ in, float* __restrict__ out,
                             const float* __restrict__ wfold, const float* __restrict__ bias,
                             int B, int Cin, int CO, int Hin)
{
  extern __shared__ float4 wlds4[];           // [4][Cin*COB + 1]
  int nt = blockDim.x, tid = threadIdx.x;
  int co0 = blockIdx.y * COB;
  int stride = Cin * COB + 1;
  int nw = Cin * COB * 4;
  const float4* wsrc = reinterpret_cast<const float4*>(wfold);
  for (int s = tid; s < nw; s += nt) {
    int p = s & 3;
    int r = s >> 2;            // col*Cin + ci  (col = local co)
    int ci = r % Cin;
    int col = r / Cin;
    wlds4[p*stride + ci*COB + col] = wsrc[(size_t)((co0 + col)*Cin + ci)*4 + p];
  }
  __syncthreads();

  int Hout = Hin * 2;
  int half = Hout >> 1;
  int total = B * Hout * half;
  int bx = xcd_swz(blockIdx.x, gridDim.x);
  int idx = bx*nt + tid;
  if (idx >= total) return;
  int x1 = idx % half;
  int y  = (idx / half) % Hout;
  int b  = idx / (half * Hout);

  int px = x1 & 1, py = y & 1;
  int X1 = x1 >> 1, Y = y >> 1;
  int X2 = X1 + (Hin >> 1);

  int r_lo = py ? Y : (Y > 0 ? Y-1 : 0);
  int r_hi = py ? (Y < Hin-1 ? Y+1 : Hin-1) : Y;
  int c1lo = px ? X1 : (X1 > 0 ? X1-1 : 0);
  int c1hi = px ? (X1 < Hin-1 ? X1+1 : Hin-1) : X1;
  int c2lo = px ? X2 : (X2 > 0 ? X2-1 : 0);
  int c2hi = px ? (X2 < Hin-1 ? X2+1 : Hin-1) : X2;

  float acc0[COB], acc1[COB];
  #pragma unroll
  for (int j = 0; j < COB; j++) { float bv = bias[co0 + j]; acc0[j] = bv; acc1[j] = bv; }

  const size_t plane = (size_t)Hin * Hin;
  const float* ibase = in + (size_t)b * Cin * plane;
  const float4* wb = wlds4 + (py*2 + px) * stride;

  for (int ci = 0; ci < Cin; ci++) {
    const float* ip = ibase + (size_t)ci * plane;
    const float* rl = ip + (size_t)r_lo * Hin;
    const float* rh = ip + (size_t)r_hi * Hin;
    float a0 = rl[c1lo], a1 = rl[c1hi];
    float a2 = rh[c1lo], a3 = rh[c1hi];
    float b0 = rl[c2lo], b1 = rl[c2hi];
    float b2 = rh[c2lo], b3 = rh[c2hi];

    const float4* wc = wb + ci * COB;
    #pragma unroll
    for (int j = 0; j < COB; j++) {
      float4 w4 = wc[j];
      acc0[j] += w4.x*a0 + w4.y*a1 + w4.z*a2 + w4.w*a3;
      acc1[j] += w4.x*b0 + w4.y*b1 + w4.z*b2 + w4.w*b3;
    }
  }

  size_t oplane = (size_t)Hout * Hout;
  size_t pix1 = (size_t)y*Hout + x1;
  float* op = out + ((size_t)b * CO + co0) * oplane;
  #pragma unroll
  for (int j = 0; j < COB; j++) {
    float v0 = acc0[j]; v0 = (v0 >= 0.f) ? v0 : 0.01f*v0;
    float v1 = acc1[j]; v1 = (v1 >= 0.f) ? v1 : 0.01f*v1;
    op[pix1] = v0;
    op[pix1 + half] = v1;
    op += oplane;              // incremental: no per-co 64-bit mul
  }
}

// ---------------- final: reflect-pad + 3x3 conv (16 -> 6) + tanh, paired x ----------------
// One thread = outputs (x0, x0+1): 12 pixel loads serve both (6/output vs 9).
// Weight addresses are loop-uniform -> s_load path. float2 coalesced stores.
__global__ void k_final2(const float* __restrict__ in, float* __restrict__ out,
                         const float* __restrict__ w, const float* __restrict__ bias)
{
  int total = 3 * HH * (WWI/2);
  int bx = xcd_swz(blockIdx.x, gridDim.x);
  int idx = bx*blockDim.x + threadIdx.x;
  if (idx >= total) return;
  int xh = idx % (WWI/2);
  int y  = (idx / (WWI/2)) % HH;
  int b  = idx / (HH * (WWI/2));
  int x0 = 2*xh;

  int ry[3];
  #pragma unroll
  for (int d = 0; d < 3; d++) {
    int t = y - 1 + d;
    t = (t < 0) ? -t : t;
    ry[d] = (t >= HH) ? (2*(HH-1) - t) : t;
  }
  // columns x0-1, x0, x0+1, x0+2 with reflect (x0 even, 0..510)
  int cx[4];
  cx[0] = (x0 == 0) ? 1 : x0-1;
  cx[1] = x0;
  cx[2] = x0+1;
  cx[3] = (x0+2 >= WWI) ? (2*(WWI-1) - (x0+2)) : x0+2;

  float acc0[6], acc1[6];
  #pragma unroll
  for (int co = 0; co < 6; co++) { float bv = bias[co]; acc0[co] = bv; acc1[co] = bv; }

  for (int ci = 0; ci < 16; ci++) {
    const float* ib = in + ((size_t)(b*16) + ci) * HWP;
    float p[3][4];
    #pragma unroll
    for (int dy = 0; dy < 3; dy++) {
      const float* r = ib + (size_t)ry[dy]*WWI;
      #pragma unroll
      for (int dx = 0; dx < 4; dx++) p[dy][dx] = r[cx[dx]];
    }
    const float* wc = w + ci*9;
    #pragma unroll
    for (int co = 0; co < 6; co++) {
      const float* wcc = wc + co*16*9;
      #pragma unroll
      for (int dy = 0; dy < 3; dy++) {
        #pragma unroll
        for (int dx = 0; dx < 3; dx++) {
          float wv = wcc[dy*3+dx];
          acc0[co] += wv * p[dy][dx];
          acc1[co] += wv * p[dy][dx+1];
        }
      }
    }
  }

  size_t pix = (size_t)y*WWI + x0;
  #pragma unroll
  for (int co = 0; co < 6; co++) {
    float2 v = make_float2(tanhf(acc0[co]), tanhf(acc1[co]));
    *reinterpret_cast<float2*>(out + ((size_t)(b*6) + co)*HWP + pix) = v;
  }
}

// ---------------- blending: fused grid-sample + weighting (all fp32) ----------------
__global__ void k_blend(const float* __restrict__ xin, const float* __restrict__ neighbors,
                        const int* __restrict__ aidx, const float* __restrict__ albedos,
                        const float* __restrict__ flows, float* __restrict__ out)
{
  int idx = blockIdx.x*blockDim.x + threadIdx.x;
  if (idx >= HWP) return;
  int xo = idx & (WWI-1);
  int yo = idx >> 9;

  float xv[9];
  #pragma unroll
  for (int i = 0; i < 9; i++) xv[i] = xin[i];

  float f0[6];
  #pragma unroll
  for (int c = 0; c < 6; c++) f0[c] = flows[(size_t)c*HWP + idx];

  const float* alb = albedos + (size_t)aidx[0]*3*HWP;
  float albp[3];
  #pragma unroll
  for (int ch = 0; ch < 3; ch++) albp[ch] = alb[(size_t)ch*HWP + idx];

  float num0 = 0.f, num1 = 0.f, num2 = 0.f;
  float wsum = 0.f;

  #pragma unroll
  for (int n = 0; n < 2; n++) {
    float dl = xv[0] - xv[(n+1)*3 + 0];
    float dv = xv[1] - xv[(n+1)*3 + 1];
    float dt = xv[2] - xv[(n+1)*3 + 2];
    bool fl = fabsf(dl) > 0.f;

    float ofx = dl*f0[0] + dv*f0[2] + dt*f0[4];
    float ofy = dl*f0[1] + dv*f0[3] + dt*f0[5];

    float gx = ((-1.f + (2.f/511.f)*(float)xo) + ofx + 1.f)*256.f - 0.5f;
    float gy = ((-1.f + (2.f/511.f)*(float)yo) + ofy + 1.f)*256.f - 0.5f;
    gx = fminf(fmaxf(gx, 0.f), 511.f);
    gy = fminf(fmaxf(gy, 0.f), 511.f);

    float x0f = floorf(gx), y0f = floorf(gy);
    float wx = gx - x0f, wy = gy - y0f;
    int x0i = (int)x0f, y0i = (int)y0f;
    int x1i = min(x0i + 1, WWI-1), y1i = min(y0i + 1, HH-1);

    float cw[4] = {(1.f-wx)*(1.f-wy), wx*(1.f-wy), (1.f-wx)*wy, wx*wy};
    int   cp[4] = {y0i*WWI + x0i, y0i*WWI + x1i, y1i*WWI + x0i, y1i*WWI + x1i};

    const float* nb = neighbors + (size_t)n*3*HWP;
    const float* Fn = flows + (size_t)(n+1)*6*HWP;

    float s0=0.f,s1=0.f,s2=0.f;
    float l0=0.f,l1=0.f,v0=0.f,v1=0.f,t0=0.f,t1=0.f;
    #pragma unroll
    for (int c = 0; c < 4; c++) {
      int p = cp[c];
      float ww = cw[c];
      float n0 = nb[p];
      float n1 = nb[HWP + p];
      float n2 = nb[2*HWP + p];
      if (fl) {
        n0 /= alb[p];
        n1 /= alb[HWP + p];
        n2 /= alb[2*HWP + p];
      }
      s0 += ww*n0; s1 += ww*n1; s2 += ww*n2;
      l0 += ww*Fn[p];             l1 += ww*Fn[HWP + p];
      v0 += ww*Fn[2*HWP + p];     v1 += ww*Fn[3*HWP + p];
      t0 += ww*Fn[4*HWP + p];     t1 += ww*Fn[5*HWP + p];
    }

    float wi0 = fl ? s0*albp[0] : s0;
    float wi1 = fl ? s1*albp[1] : s1;
    float wi2 = fl ? s2*albp[2] : s2;

    float obx = dl*l0 + dv*v0 + dt*t0;
    float oby = dl*l1 + dv*v1 + dt*t1;
    float dist = fabsf(ofx - obx) + fabsf(ofy - oby);
    float wgt = expf(-51.2f * dist);

    wsum += wgt;
    num0 += wgt*wi0; num1 += wgt*wi1; num2 += wgt*wi2;
  }

  float inv = 1.f / (wsum + 1e-5f);
  out[idx]         = num0*inv;
  out[HWP + idx]   = num1*inv;
  out[2*HWP + idx] = num2*inv;
}

// ---------------- launch ----------------
extern "C" void kernel_launch(void* const* d_in, const int* in_sizes, int n_in,
                              void* d_out, int out_size, void* d_ws, size_t ws_size,
                              hipStream_t stream) {
  const float* x         = (const float*)d_in[0];
  const float* neighbors = (const float*)d_in[1];
  const int*   aidx      = (const int*)d_in[2];
  const float* wts[10];
  const float* bis[10];
  for (int i = 0; i < 9; i++) { wts[i] = (const float*)d_in[3+2*i]; bis[i] = (const float*)d_in[4+2*i]; }
  wts[9] = (const float*)d_in[21];   // wf
  bis[9] = (const float*)d_in[22];   // bf
  const float* albedos = (const float*)d_in[23];

  float* wk   = (float*)d_ws;
  float* bufS = wk;                   // 792 floats (layer0 out)
  float* bufA = wk + 800;             // up to 4,718,592 floats
  float* bufB = bufA + 4718592;       // up to 12,582,912 floats
  size_t need = (size_t)(800 + 4718592 + 12582912) * 4;
  if (ws_size < need) return;

  // Folded weights in bufA slack [3,200,000, 3,415,040): above L7's peak bufA
  // use (3,145,728 floats); overwritten only by k_final (4,718,592) AFTER L8
  // consumed them. No workspace growth.
  float* wf1 = bufA + 3200000;            // 64*66*16 = 67584
  float* wf2 = wf1 + 67584;               // 64*64*16 = 65536
  float* wf3 = wf2 + 65536;               // 32*64*16 = 32768
  float* wf4 = wf3 + 32768;               // 32*32*16 = 16384
  float* wf5 = wf4 + 16384;               // 32*32*16 = 16384
  float* wf6 = wf5 + 16384;               // 16*32*16 = 8192
  float* wf7 = wf6 + 8192;                // 16*16*16 = 4096
  float* wf8 = wf7 + 4096;                // 16*16*16 = 4096
  k_foldw8<<<53, 256, 0, stream>>>(wts[1], wts[2], wts[3], wts[4], wts[5], wts[6], wts[7], wts[8],
                                   wf1, wf2, wf3, wf4, wf5, wf6, wf7, wf8);

  k_layer0<<<1, 256, 0, stream>>>(x, wts[0], bis[0], bufS);

  auto blocks = [](int total){ return (total + 255) / 256; };

  // L1-L5: scalar parity upconv, grid (npix/256, CO). LDS = 4*(Cin+1)*16 B.
  {
    dim3 g1(blocks(3*4*4), 64), g2(blocks(3*8*8), 64);
    dim3 g3(blocks(3*16*16), 32), g4(blocks(3*32*32), 32), g5(blocks(3*64*64), 32);
    k_upconv_s<<<g1, 256, (size_t)4*(66+1)*16, stream>>>(bufS, bufA, wf1, bis[1], 3, 66, 64, 2);
    k_upconv_s<<<g2, 256, (size_t)4*(64+1)*16, stream>>>(bufA, bufB, wf2, bis[2], 3, 64, 64, 4);
    k_upconv_s<<<g3, 256, (size_t)4*(64+1)*16, stream>>>(bufB, bufA, wf3, bis[3], 3, 64, 32, 8);
    k_upconv_s<<<g4, 256, (size_t)4*(32+1)*16, stream>>>(bufA, bufB, wf4, bis[4], 3, 32, 32, 16);
    k_upconv_s<<<g5, 256, (size_t)4*(32+1)*16, stream>>>(bufB, bufA, wf5, bis[5], 3, 32, 32, 32);
  }

  // L6: thread-per-output pixel, padded LDS weights (+XCD swizzle, 192 blocks).
  k_upconv_w<16><<<blocks(3*128*128), 256, (size_t)4*(32*16+1)*16, stream>>>(bufA, bufB, wf6, bis[6], 3, 32, 64);
  // L7: paired + co-split x2 (proven 44-VGPR shape; was the spilling <16>).
  {
    dim3 g7(blocks(3*256*128), 2);
    k_upconv_w2c<8><<<g7, 256, (size_t)4*(16*8+1)*16, stream>>>(bufB, bufA, wf7, bis[7], 3, 16, 16, 128);
  }
  // L8: paired + co-split x2 (+XCD swizzle for row-sharing L2 reuse).
  {
    dim3 g8(blocks(3*512*256), 2);
    k_upconv_w2c<8><<<g8, 256, (size_t)4*(16*8+1)*16, stream>>>(bufA, bufB, wf8, bis[8], 3, 16, 16, 256);
  }

  // final: paired-x conv + tanh (+XCD swizzle).
  k_final2<<<blocks(3*HH*(WWI/2)), 256, 0, stream>>>(bufB, bufA, wts[9], bis[9]);
  k_blend<<<blocks(HWP), 256, 0, stream>>>(x, neighbors, aidx, albedos, bufA, (float*)d_out);
}

// Round 12
// 302.263 us; speedup vs baseline: 1.8501x; 1.0205x over previous
//
#include <hip/hip_runtime.h>
#include <hip/hip_bf16.h>
#include <math.h>

// All inputs and the output are FLOAT32 (reference dtype). The "bf16" in the
// harness label is a literal string, not a dtype indicator.
//
// Upconv history (compressed):
//  R1-R4: multi-output kernels spill (excess WRITE_SIZE tell). R5: per-lane
//  weight addrs -> vector L1 traffic. R6: s_load weights -> serial chains on
//  tiny grids. R7/R8: LDS parity weights (+1-float4 pad = disjoint banks) +
//  paired outputs. R9: COB=8 co-split kills spill (VGPR 44). R10: XCD swizzle
//  cuts L8 FETCH 49->9.3MB but dur 47->46us: L8 is LDS-ISSUE-BOUND
//  (128 ds_read_b128/wave x 12cyc on the one LDS unit/CU ~= 31us vs VALU 10us).
//  Now: P=4 positions/thread (same px parity, stride Hout/4) x COB=4 ->
//  ds_read per output-scalar 8 -> 4 (L6: 32 -> 8). acc[4][4]=16 regs.

#define HH 512
#define WWI 512
#define HWP (HH*WWI)

// Contiguous-chunk XCD swizzle (bijective when nwg % 8 == 0).
__device__ __forceinline__ int xcd_swz(int bx, int nbx) {
  if ((nbx & 7) == 0) {
    int c = nbx >> 3;
    return (bx & 7) * c + (bx >> 3);
  }
  return bx;
}

// ---------------- layer 0: 1x1 conv on upsampled 2x2 + leakyrelu + coordconv ----------------
__global__ void k_layer0(const float* __restrict__ xin, const float* __restrict__ w,
                         const float* __restrict__ bias, float* __restrict__ out)
{
  for (int idx = threadIdx.x; idx < 3*66*4; idx += blockDim.x) {
    int pos = idx & 3;
    int c = (idx >> 2) % 66;
    int b = idx / (66*4);
    float v;
    if (c < 64) {
      float a = bias[c];
      #pragma unroll
      for (int ci = 0; ci < 3; ci++) a += w[c*3+ci] * xin[b*3+ci];
      v = (a >= 0.f) ? a : 0.01f*a;
    } else {
      int xx = pos & 1, yy = pos >> 1;
      v = (c == 64) ? 2.f*(float)xx : 2.f*(float)yy;
    }
    out[idx] = v;
  }
}

// ---------------- weight folding for upsample-conv parity decomposition ----------------
// upsample x2 + reflect-pad + 3x3 VALID conv == per-output-parity 2x2 conv on the
// ORIGINAL image (border reflect == clamp outer row/col; verified all Hin >= 2).
// Folded layout: f[((co*Cin + ci)*16) + p*4 + ky*2 + kx], p = py*2+px.
__global__ void k_foldw8(const float* __restrict__ w1, const float* __restrict__ w2,
                         const float* __restrict__ w3, const float* __restrict__ w4,
                         const float* __restrict__ w5, const float* __restrict__ w6,
                         const float* __restrict__ w7, const float* __restrict__ w8,
                         float* __restrict__ f1, float* __restrict__ f2,
                         float* __restrict__ f3, float* __restrict__ f4,
                         float* __restrict__ f5, float* __restrict__ f6,
                         float* __restrict__ f7, float* __restrict__ f8)
{
  int idx = blockIdx.x*blockDim.x + threadIdx.x;
  const float* w; float* f; int n;
  if      (idx < 4224)  { w = w1; f = f1; n = idx; }          // L1: 64x66
  else if (idx < 8320)  { w = w2; f = f2; n = idx - 4224; }   // L2: 64x64
  else if (idx < 10368) { w = w3; f = f3; n = idx - 8320; }   // L3: 32x64
  else if (idx < 11392) { w = w4; f = f4; n = idx - 10368; }  // L4: 32x32
  else if (idx < 12416) { w = w5; f = f5; n = idx - 11392; }  // L5: 32x32
  else if (idx < 12928) { w = w6; f = f6; n = idx - 12416; }  // L6: 16x32
  else if (idx < 13184) { w = w7; f = f7; n = idx - 12928; }  // L7: 16x16
  else if (idx < 13440) { w = w8; f = f8; n = idx - 13184; }  // L8: 16x16
  else return;

  const float* ws = w + (size_t)n*9;
  float W[9];
  #pragma unroll
  for (int k = 0; k < 9; k++) W[k] = ws[k];

  float a[2][2][3];
  #pragma unroll
  for (int c = 0; c < 3; c++) {
    a[0][0][c] = W[c];          a[0][1][c] = W[3+c] + W[6+c];
    a[1][0][c] = W[c] + W[3+c]; a[1][1][c] = W[6+c];
  }
  float* fo = f + (size_t)n*16;
  #pragma unroll
  for (int py = 0; py < 2; py++)
    #pragma unroll
    for (int px = 0; px < 2; px++) {
      int p = py*2 + px;
      #pragma unroll
      for (int ky = 0; ky < 2; ky++) {
        float kx0 = (px == 0) ? a[py][ky][0] : (a[py][ky][0] + a[py][ky][1]);
        float kx1 = (px == 0) ? (a[py][ky][1] + a[py][ky][2]) : a[py][ky][2];
        fo[p*4 + ky*2 + 0] = kx0;
        fo[p*4 + ky*2 + 1] = kx1;
      }
    }
}

// ---------------- scalar parity upconv: one thread per OUTPUT SCALAR ----------------
// blockIdx.y = co. LDS: that co's 4 parity weight sets, [p][ci], stride Cin+1
// float4s (parity blocks bank-offset 4 -> disjoint).
__global__ void k_upconv_s(const float* __restrict__ in, float* __restrict__ out,
                           const float* __restrict__ wfold, const float* __restrict__ bias,
                           int B, int Cin, int CO, int Hin)
{
  extern __shared__ float4 wlds4[];            // [4][Cin+1]
  int nt = blockDim.x, tid = threadIdx.x;
  int co = blockIdx.y;
  int stride = Cin + 1;
  const float4* wsrc = reinterpret_cast<const float4*>(wfold);
  for (int s = tid; s < Cin*4; s += nt) {
    int p = s & 3;
    int ci = s >> 2;
    wlds4[p*stride + ci] = wsrc[(size_t)(co*Cin + ci)*4 + p];
  }
  __syncthreads();

  int Hout = Hin * 2;
  int npix = B * Hout * Hout;
  int idx = blockIdx.x*nt + tid;
  if (idx >= npix) return;
  int x = idx % Hout;
  int y = (idx / Hout) % Hout;
  int b = idx / (Hout * Hout);

  int X = x >> 1, Y = y >> 1;
  int px = x & 1, py = y & 1;

  int r_lo = py ? Y : (Y > 0 ? Y-1 : 0);
  int r_hi = py ? (Y < Hin-1 ? Y+1 : Hin-1) : Y;
  int c_lo = px ? X : (X > 0 ? X-1 : 0);
  int c_hi = px ? (X < Hin-1 ? X+1 : Hin-1) : X;

  float acc = bias[co];

  const size_t plane = (size_t)Hin * Hin;
  const float* ibase = in + (size_t)b * Cin * plane;
  const float4* wb = wlds4 + (py*2 + px) * stride;

  for (int ci = 0; ci < Cin; ci++) {
    const float* ip = ibase + (size_t)ci * plane;
    const float* rl = ip + (size_t)r_lo * Hin;
    const float* rh = ip + (size_t)r_hi * Hin;
    float4 w4 = wb[ci];
    acc += w4.x*rl[c_lo] + w4.y*rl[c_hi] + w4.z*rh[c_lo] + w4.w*rh[c_hi];
  }

  float v = (acc >= 0.f) ? acc : 0.01f*acc;
  out[((size_t)b*CO + co)*((size_t)Hout*Hout) + (size_t)y*Hout + x] = v;
}

// ---------------- P-position + co-split LDS-weight upconv ----------------
// One thread = P x-positions (x1 + k*Hout/P, same px parity since Hout/P even)
// x COB channels; blockIdx.y = co-slice. One ds_read_b128 feeds 4*P FMAs ->
// ds_read per output-scalar = Cin/P. acc[P][COB] = 16 regs at P=4,COB=4.
template<int COB, int P>
__global__ void k_upconv_wP(const float* __restrict__ in, float* __restrict__ out,
                            const float* __restrict__ wfold, const float* __restrict__ bias,
                            int B, int Cin, int CO, int Hin)
{
  extern __shared__ float4 wlds4[];           // [4][Cin*COB + 1]
  int nt = blockDim.x, tid = threadIdx.x;
  int co0 = blockIdx.y * COB;
  int stride = Cin * COB + 1;                 // +1 float4 pad -> parity blocks on disjoint banks
  int nw = Cin * COB * 4;
  const float4* wsrc = reinterpret_cast<const float4*>(wfold);
  for (int s = tid; s < nw; s += nt) {
    int p = s & 3;
    int r = s >> 2;            // col*Cin + ci  (col = local co)
    int ci = r % Cin;
    int col = r / Cin;
    wlds4[p*stride + ci*COB + col] = wsrc[(size_t)((co0 + col)*Cin + ci)*4 + p];
  }
  __syncthreads();

  int Hout = Hin * 2;
  int q = Hout / P;                           // even for P in {2,4} and Hout >= 8
  int total = B * Hout * q;
  int bx = xcd_swz(blockIdx.x, gridDim.x);
  int idx = bx*nt + tid;
  if (idx >= total) return;
  int x1 = idx % q;
  int y  = (idx / q) % Hout;
  int b  = idx / (q * Hout);

  int px = x1 & 1, py = y & 1;
  int Y = y >> 1;
  int r_lo = py ? Y : (Y > 0 ? Y-1 : 0);
  int r_hi = py ? (Y < Hin-1 ? Y+1 : Hin-1) : Y;

  int clo[P], chi[P];
  #pragma unroll
  for (int k = 0; k < P; k++) {
    int X = (x1 + k*q) >> 1;
    clo[k] = px ? X : (X > 0 ? X-1 : 0);
    chi[k] = px ? (X < Hin-1 ? X+1 : Hin-1) : X;
  }

  float acc[P][COB];
  #pragma unroll
  for (int j = 0; j < COB; j++) {
    float bv = bias[co0 + j];
    #pragma unroll
    for (int k = 0; k < P; k++) acc[k][j] = bv;
  }

  const size_t plane = (size_t)Hin * Hin;
  const float* ibase = in + (size_t)b * Cin * plane;
  const float4* wb = wlds4 + (py*2 + px) * stride;

  for (int ci = 0; ci < Cin; ci++) {
    const float* ip = ibase + (size_t)ci * plane;
    const float* rl = ip + (size_t)r_lo * Hin;
    const float* rh = ip + (size_t)r_hi * Hin;
    float pl0[P], pl1[P], ph0[P], ph1[P];
    #pragma unroll
    for (int k = 0; k < P; k++) {
      pl0[k] = rl[clo[k]]; pl1[k] = rl[chi[k]];
      ph0[k] = rh[clo[k]]; ph1[k] = rh[chi[k]];
    }
    const float4* wc = wb + ci * COB;
    #pragma unroll
    for (int j = 0; j < COB; j++) {
      float4 w4 = wc[j];                      // 1 ds_read_b128 -> 4*P FMAs
      #pragma unroll
      for (int k = 0; k < P; k++)
        acc[k][j] += w4.x*pl0[k] + w4.y*pl1[k] + w4.z*ph0[k] + w4.w*ph1[k];
    }
  }

  size_t oplane = (size_t)Hout * Hout;
  float* op = out + ((size_t)b * CO + co0) * oplane + (size_t)y*Hout + x1;
  #pragma unroll
  for (int j = 0; j < COB; j++) {
    #pragma unroll
    for (int k = 0; k < P; k++) {
      float v = acc[k][j];
      v = (v >= 0.f) ? v : 0.01f*v;
      op[k*q] = v;
    }
    op += oplane;              // incremental: no per-co 64-bit mul
  }
}

// ---------------- final: reflect-pad + 3x3 conv (16 -> 6) + tanh, paired x ----------------
// One thread = outputs (x0, x0+1): 12 pixel loads serve both (6/output vs 9).
// Weight addresses are loop-uniform -> s_load path. float2 coalesced stores.
__global__ void k_final2(const float* __restrict__ in, float* __restrict__ out,
                         const float* __restrict__ w, const float* __restrict__ bias)
{
  int total = 3 * HH * (WWI/2);
  int bx = xcd_swz(blockIdx.x, gridDim.x);
  int idx = bx*blockDim.x + threadIdx.x;
  if (idx >= total) return;
  int xh = idx % (WWI/2);
  int y  = (idx / (WWI/2)) % HH;
  int b  = idx / (HH * (WWI/2));
  int x0 = 2*xh;

  int ry[3];
  #pragma unroll
  for (int d = 0; d < 3; d++) {
    int t = y - 1 + d;
    t = (t < 0) ? -t : t;
    ry[d] = (t >= HH) ? (2*(HH-1) - t) : t;
  }
  // columns x0-1, x0, x0+1, x0+2 with reflect (x0 even, 0..510)
  int cx[4];
  cx[0] = (x0 == 0) ? 1 : x0-1;
  cx[1] = x0;
  cx[2] = x0+1;
  cx[3] = (x0+2 >= WWI) ? (2*(WWI-1) - (x0+2)) : x0+2;

  float acc0[6], acc1[6];
  #pragma unroll
  for (int co = 0; co < 6; co++) { float bv = bias[co]; acc0[co] = bv; acc1[co] = bv; }

  for (int ci = 0; ci < 16; ci++) {
    const float* ib = in + ((size_t)(b*16) + ci) * HWP;
    float p[3][4];
    #pragma unroll
    for (int dy = 0; dy < 3; dy++) {
      const float* r = ib + (size_t)ry[dy]*WWI;
      #pragma unroll
      for (int dx = 0; dx < 4; dx++) p[dy][dx] = r[cx[dx]];
    }
    const float* wc = w + ci*9;
    #pragma unroll
    for (int co = 0; co < 6; co++) {
      const float* wcc = wc + co*16*9;
      #pragma unroll
      for (int dy = 0; dy < 3; dy++) {
        #pragma unroll
        for (int dx = 0; dx < 3; dx++) {
          float wv = wcc[dy*3+dx];
          acc0[co] += wv * p[dy][dx];
          acc1[co] += wv * p[dy][dx+1];
        }
      }
    }
  }

  size_t pix = (size_t)y*WWI + x0;
  #pragma unroll
  for (int co = 0; co < 6; co++) {
    float2 v = make_float2(tanhf(acc0[co]), tanhf(acc1[co]));
    *reinterpret_cast<float2*>(out + ((size_t)(b*6) + co)*HWP + pix) = v;
  }
}

// ---------------- blending: fused grid-sample + weighting (all fp32) ----------------
__global__ void k_blend(const float* __restrict__ xin, const float* __restrict__ neighbors,
                        const int* __restrict__ aidx, const float* __restrict__ albedos,
                        const float* __restrict__ flows, float* __restrict__ out)
{
  int idx = blockIdx.x*blockDim.x + threadIdx.x;
  if (idx >= HWP) return;
  int xo = idx & (WWI-1);
  int yo = idx >> 9;

  float xv[9];
  #pragma unroll
  for (int i = 0; i < 9; i++) xv[i] = xin[i];

  float f0[6];
  #pragma unroll
  for (int c = 0; c < 6; c++) f0[c] = flows[(size_t)c*HWP + idx];

  const float* alb = albedos + (size_t)aidx[0]*3*HWP;
  float albp[3];
  #pragma unroll
  for (int ch = 0; ch < 3; ch++) albp[ch] = alb[(size_t)ch*HWP + idx];

  float num0 = 0.f, num1 = 0.f, num2 = 0.f;
  float wsum = 0.f;

  #pragma unroll
  for (int n = 0; n < 2; n++) {
    float dl = xv[0] - xv[(n+1)*3 + 0];
    float dv = xv[1] - xv[(n+1)*3 + 1];
    float dt = xv[2] - xv[(n+1)*3 + 2];
    bool fl = fabsf(dl) > 0.f;

    float ofx = dl*f0[0] + dv*f0[2] + dt*f0[4];
    float ofy = dl*f0[1] + dv*f0[3] + dt*f0[5];

    float gx = ((-1.f + (2.f/511.f)*(float)xo) + ofx + 1.f)*256.f - 0.5f;
    float gy = ((-1.f + (2.f/511.f)*(float)yo) + ofy + 1.f)*256.f - 0.5f;
    gx = fminf(fmaxf(gx, 0.f), 511.f);
    gy = fminf(fmaxf(gy, 0.f), 511.f);

    float x0f = floorf(gx), y0f = floorf(gy);
    float wx = gx - x0f, wy = gy - y0f;
    int x0i = (int)x0f, y0i = (int)y0f;
    int x1i = min(x0i + 1, WWI-1), y1i = min(y0i + 1, HH-1);

    float cw[4] = {(1.f-wx)*(1.f-wy), wx*(1.f-wy), (1.f-wx)*wy, wx*wy};
    int   cp[4] = {y0i*WWI + x0i, y0i*WWI + x1i, y1i*WWI + x0i, y1i*WWI + x1i};

    const float* nb = neighbors + (size_t)n*3*HWP;
    const float* Fn = flows + (size_t)(n+1)*6*HWP;

    float s0=0.f,s1=0.f,s2=0.f;
    float l0=0.f,l1=0.f,v0=0.f,v1=0.f,t0=0.f,t1=0.f;
    #pragma unroll
    for (int c = 0; c < 4; c++) {
      int p = cp[c];
      float ww = cw[c];
      float n0 = nb[p];
      float n1 = nb[HWP + p];
      float n2 = nb[2*HWP + p];
      if (fl) {
        n0 /= alb[p];
        n1 /= alb[HWP + p];
        n2 /= alb[2*HWP + p];
      }
      s0 += ww*n0; s1 += ww*n1; s2 += ww*n2;
      l0 += ww*Fn[p];             l1 += ww*Fn[HWP + p];
      v0 += ww*Fn[2*HWP + p];     v1 += ww*Fn[3*HWP + p];
      t0 += ww*Fn[4*HWP + p];     t1 += ww*Fn[5*HWP + p];
    }

    float wi0 = fl ? s0*albp[0] : s0;
    float wi1 = fl ? s1*albp[1] : s1;
    float wi2 = fl ? s2*albp[2] : s2;

    float obx = dl*l0 + dv*v0 + dt*t0;
    float oby = dl*l1 + dv*v1 + dt*t1;
    float dist = fabsf(ofx - obx) + fabsf(ofy - oby);
    float wgt = expf(-51.2f * dist);

    wsum += wgt;
    num0 += wgt*wi0; num1 += wgt*wi1; num2 += wgt*wi2;
  }

  float inv = 1.f / (wsum + 1e-5f);
  out[idx]         = num0*inv;
  out[HWP + idx]   = num1*inv;
  out[2*HWP + idx] = num2*inv;
}

// ---------------- launch ----------------
extern "C" void kernel_launch(void* const* d_in, const int* in_sizes, int n_in,
                              void* d_out, int out_size, void* d_ws, size_t ws_size,
                              hipStream_t stream) {
  const float* x         = (const float*)d_in[0];
  const float* neighbors = (const float*)d_in[1];
  const int*   aidx      = (const int*)d_in[2];
  const float* wts[10];
  const float* bis[10];
  for (int i = 0; i < 9; i++) { wts[i] = (const float*)d_in[3+2*i]; bis[i] = (const float*)d_in[4+2*i]; }
  wts[9] = (const float*)d_in[21];   // wf
  bis[9] = (const float*)d_in[22];   // bf
  const float* albedos = (const float*)d_in[23];

  float* wk   = (float*)d_ws;
  float* bufS = wk;                   // 792 floats (layer0 out)
  float* bufA = wk + 800;             // up to 4,718,592 floats
  float* bufB = bufA + 4718592;       // up to 12,582,912 floats
  size_t need = (size_t)(800 + 4718592 + 12582912) * 4;
  if (ws_size < need) return;

  // Folded weights in bufA slack [3,200,000, 3,415,040): above L7's peak bufA
  // use (3,145,728 floats); overwritten only by k_final (4,718,592) AFTER L8
  // consumed them. No workspace growth.
  float* wf1 = bufA + 3200000;            // 64*66*16 = 67584
  float* wf2 = wf1 + 67584;               // 64*64*16 = 65536
  float* wf3 = wf2 + 65536;               // 32*64*16 = 32768
  float* wf4 = wf3 + 32768;               // 32*32*16 = 16384
  float* wf5 = wf4 + 16384;               // 32*32*16 = 16384
  float* wf6 = wf5 + 16384;               // 16*32*16 = 8192
  float* wf7 = wf6 + 8192;                // 16*16*16 = 4096
  float* wf8 = wf7 + 4096;                // 16*16*16 = 4096
  k_foldw8<<<53, 256, 0, stream>>>(wts[1], wts[2], wts[3], wts[4], wts[5], wts[6], wts[7], wts[8],
                                   wf1, wf2, wf3, wf4, wf5, wf6, wf7, wf8);

  k_layer0<<<1, 256, 0, stream>>>(x, wts[0], bis[0], bufS);

  auto blocks = [](int total){ return (total + 255) / 256; };

  // L1-L5: scalar parity upconv, grid (npix/256, CO). LDS = 4*(Cin+1)*16 B.
  {
    dim3 g1(blocks(3*4*4), 64), g2(blocks(3*8*8), 64);
    dim3 g3(blocks(3*16*16), 32), g4(blocks(3*32*32), 32), g5(blocks(3*64*64), 32);
    k_upconv_s<<<g1, 256, (size_t)4*(66+1)*16, stream>>>(bufS, bufA, wf1, bis[1], 3, 66, 64, 2);
    k_upconv_s<<<g2, 256, (size_t)4*(64+1)*16, stream>>>(bufA, bufB, wf2, bis[2], 3, 64, 64, 4);
    k_upconv_s<<<g3, 256, (size_t)4*(64+1)*16, stream>>>(bufB, bufA, wf3, bis[3], 3, 64, 32, 8);
    k_upconv_s<<<g4, 256, (size_t)4*(32+1)*16, stream>>>(bufA, bufB, wf4, bis[4], 3, 32, 32, 16);
    k_upconv_s<<<g5, 256, (size_t)4*(32+1)*16, stream>>>(bufB, bufA, wf5, bis[5], 3, 32, 32, 32);
  }

  // L6-L8: P=4 positions x COB=4 channels per thread (ds_read/output = Cin/4).
  // LDS = 4*(Cin*4+1)*16 B. Grid-x divisible by 8 -> XCD swizzle active.
  {
    dim3 g6(blocks(3*128*32), 4);    // 48 x 4
    dim3 g7(blocks(3*256*64), 4);    // 192 x 4
    dim3 g8(blocks(3*512*128), 4);   // 768 x 4
    k_upconv_wP<4,4><<<g6, 256, (size_t)4*(32*4+1)*16, stream>>>(bufA, bufB, wf6, bis[6], 3, 32, 16, 64);
    k_upconv_wP<4,4><<<g7, 256, (size_t)4*(16*4+1)*16, stream>>>(bufB, bufA, wf7, bis[7], 3, 16, 16, 128);
    k_upconv_wP<4,4><<<g8, 256, (size_t)4*(16*4+1)*16, stream>>>(bufA, bufB, wf8, bis[8], 3, 16, 16, 256);
  }

  // final: paired-x conv + tanh (+XCD swizzle).
  k_final2<<<blocks(3*HH*(WWI/2)), 256, 0, stream>>>(bufB, bufA, wts[9], bis[9]);
  k_blend<<<blocks(HWP), 256, 0, stream>>>(x, neighbors, aidx, albedos, bufA, (float*)d_out);
}